// Round 4
// baseline (1692.881 us; speedup 1.0000x reference)
//
#include <hip/hip_runtime.h>
#include <math.h>

#define BB 4
#define SS 1024
#define DM 1024
#define HH 16
#define DKK 64
#define NTOK (BB*SS)   // 4096
#define QT 16          // q-rows per attn block

// ============================================================
// GEMM: Y = X @ W^T + bias
// X: [4096,1024] rm, W: [1024,1024] rm. 64x64 tile, 256 thr,
// 4x4 micro-tile, BK=32, register prefetch (global latency
// hidden under the 32-kk compute). Grid 16x64 = 1024 blocks
// = 4 blocks/CU = 16 waves/CU.
// ============================================================
template<bool HEAD_OUT>
__global__ __launch_bounds__(256) void gemm_xwT(
    const float* __restrict__ X, const float* __restrict__ W,
    const float* __restrict__ bias, float* __restrict__ Y)
{
    __shared__ float Xs[32][68];   // [k][m]
    __shared__ float Ws[32][68];   // [k][o]

    const int tid = threadIdx.x;
    const int m0 = blockIdx.y * 64;
    const int o0 = blockIdx.x * 64;
    const int lr = tid >> 3;          // 0..31 loader row
    const int lk = (tid & 7) << 2;    // k offset 0,4,..,28
    const int tm = tid >> 4;          // 0..15
    const int tn = tid & 15;          // 0..15

    const float* Xp = &X[(size_t)(m0 + lr) * 1024 + lk];
    const float* Wp = &W[(size_t)(o0 + lr) * 1024 + lk];

    float4 xa0 = *(const float4*)&Xp[0];
    float4 xa1 = *(const float4*)&Xp[32 * 1024];
    float4 wa0 = *(const float4*)&Wp[0];
    float4 wa1 = *(const float4*)&Wp[32 * 1024];

    float acc[4][4] = {};

    for (int kt = 0; kt < 1024; kt += 32) {
        __syncthreads();   // previous iteration's LDS reads done
        Xs[lk+0][lr]    = xa0.x; Xs[lk+1][lr]    = xa0.y; Xs[lk+2][lr]    = xa0.z; Xs[lk+3][lr]    = xa0.w;
        Xs[lk+0][lr+32] = xa1.x; Xs[lk+1][lr+32] = xa1.y; Xs[lk+2][lr+32] = xa1.z; Xs[lk+3][lr+32] = xa1.w;
        Ws[lk+0][lr]    = wa0.x; Ws[lk+1][lr]    = wa0.y; Ws[lk+2][lr]    = wa0.z; Ws[lk+3][lr]    = wa0.w;
        Ws[lk+0][lr+32] = wa1.x; Ws[lk+1][lr+32] = wa1.y; Ws[lk+2][lr+32] = wa1.z; Ws[lk+3][lr+32] = wa1.w;
        __syncthreads();
        if (kt + 32 < 1024) {          // issue next-tile loads, hide under compute
            xa0 = *(const float4*)&Xp[kt + 32];
            xa1 = *(const float4*)&Xp[kt + 32 + 32 * 1024];
            wa0 = *(const float4*)&Wp[kt + 32];
            wa1 = *(const float4*)&Wp[kt + 32 + 32 * 1024];
        }
        #pragma unroll
        for (int kk = 0; kk < 32; ++kk) {
            const float4 a4 = *(const float4*)&Xs[kk][tm*4];   // 8-lane bcast, free
            const float4 b4 = *(const float4*)&Ws[kk][tn*4];   // contig per 8 lanes, free
            acc[0][0] = fmaf(a4.x, b4.x, acc[0][0]); acc[0][1] = fmaf(a4.x, b4.y, acc[0][1]);
            acc[0][2] = fmaf(a4.x, b4.z, acc[0][2]); acc[0][3] = fmaf(a4.x, b4.w, acc[0][3]);
            acc[1][0] = fmaf(a4.y, b4.x, acc[1][0]); acc[1][1] = fmaf(a4.y, b4.y, acc[1][1]);
            acc[1][2] = fmaf(a4.y, b4.z, acc[1][2]); acc[1][3] = fmaf(a4.y, b4.w, acc[1][3]);
            acc[2][0] = fmaf(a4.z, b4.x, acc[2][0]); acc[2][1] = fmaf(a4.z, b4.y, acc[2][1]);
            acc[2][2] = fmaf(a4.z, b4.z, acc[2][2]); acc[2][3] = fmaf(a4.z, b4.w, acc[2][3]);
            acc[3][0] = fmaf(a4.w, b4.x, acc[3][0]); acc[3][1] = fmaf(a4.w, b4.y, acc[3][1]);
            acc[3][2] = fmaf(a4.w, b4.z, acc[3][2]); acc[3][3] = fmaf(a4.w, b4.w, acc[3][3]);
        }
    }

    const float4 b4 = *(const float4*)&bias[o0 + tn*4];
    #pragma unroll
    for (int i = 0; i < 4; ++i) {
        const int m = m0 + tm*4 + i;
        float4 o;
        o.x = acc[i][0] + b4.x; o.y = acc[i][1] + b4.y;
        o.z = acc[i][2] + b4.z; o.w = acc[i][3] + b4.w;
        if (HEAD_OUT) {
            const int b_ = m >> 10, s_ = m & 1023;
            const int oc = o0 + tn*4;             // 4-aligned, never crosses head
            const int h_ = oc >> 6, d_ = oc & 63;
            *(float4*)&Y[(((size_t)(b_*HH + h_))*SS + s_)*DKK + d_] = o;
        } else {
            *(float4*)&Y[(size_t)m*1024 + o0 + tn*4] = o;
        }
    }
}

// ============================================================
// Fused attention, 16 q-rows per block, 8 waves (512 thr).
// launch_bounds(512,4) -> VGPR<=128 -> 2 blocks/CU x 8 waves
// = 16 waves/CU. Phase1: QK^T, wave covers 128 k-rows (K in
// regs, half-row at a time). Phase2: wave owns 2 rows; 4
// PARALLEL 6-step scans (ILP) instead of serial carry chain.
// Phase3: PV k split 8-way; LDS partial reduction.
// ============================================================
__global__ __launch_bounds__(512, 4) void attn_kernel(
    const float* __restrict__ Qh, const float* __restrict__ Kh,
    const float* __restrict__ Vh, const float* __restrict__ gammas,
    float* __restrict__ Ao)
{
    __shared__ float sS[QT][1024];   // 64 KB score rows
    __shared__ float sQ[QT][64];     // 4 KB

    const int tid  = threadIdx.x;
    const int lane = tid & 63;
    const int w    = tid >> 6;       // 0..7

    // XCD-bijective swizzle: 4096 blocks -> 512 contiguous per XCD
    const int bid = ((blockIdx.x & 7) << 9) | (blockIdx.x >> 3);
    const int bh  = bid >> 6;
    const int qt  = bid & 63;
    const int q0  = qt * QT;
    const int h   = bh & (HH - 1);
    const int b_  = bh >> 4;

    const float* Qb = Qh + (size_t)bh * SS * DKK;
    const float* Kb = Kh + (size_t)bh * SS * DKK;
    const float* Vb = Vh + (size_t)bh * SS * DKK;

    const float g = gammas[h];
    const float gamma = -(fmaxf(g, 0.f) + log1pf(__expf(-fabsf(g))));

    {   // load Q tile: 512 thr x float2
        const int r = tid >> 5, c2 = (tid & 31) << 1;
        *(float2*)&sQ[r][c2] = *(const float2*)&Qb[(size_t)(q0 + r)*DKK + c2];
    }
    __syncthreads();

    // ---------- phase 1: QK^T; wave w covers k = i*512 + w*64 + lane ----------
    #pragma unroll 1
    for (int i = 0; i < 2; ++i) {
        const int kk = i*512 + w*64 + lane;
        const float* Krow = &Kb[(size_t)kk * DKK];
        float accr[QT];
        {   // first half of the dot (c = 0..31)
            float4 kr[8];
            #pragma unroll
            for (int c = 0; c < 8; ++c) kr[c] = *(const float4*)&Krow[c*4];
            #pragma unroll
            for (int r = 0; r < QT; ++r) {
                float a = 0.f;
                #pragma unroll
                for (int c = 0; c < 8; ++c) {
                    const float4 q4 = *(const float4*)&sQ[r][c*4];  // bcast, free
                    a = fmaf(kr[c].x, q4.x, a); a = fmaf(kr[c].y, q4.y, a);
                    a = fmaf(kr[c].z, q4.z, a); a = fmaf(kr[c].w, q4.w, a);
                }
                accr[r] = a;
            }
        }
        {   // second half (c = 32..63)
            float4 kr[8];
            #pragma unroll
            for (int c = 0; c < 8; ++c) kr[c] = *(const float4*)&Krow[32 + c*4];
            #pragma unroll
            for (int r = 0; r < QT; ++r) {
                float a = accr[r];
                #pragma unroll
                for (int c = 0; c < 8; ++c) {
                    const float4 q4 = *(const float4*)&sQ[r][32 + c*4];
                    a = fmaf(kr[c].x, q4.x, a); a = fmaf(kr[c].y, q4.y, a);
                    a = fmaf(kr[c].z, q4.z, a); a = fmaf(kr[c].w, q4.w, a);
                }
                sS[r][kk] = a * 0.125f;   // 1/sqrt(64)
            }
        }
    }
    __syncthreads();

    // ---------- phase 2: wave w owns rows 2w, 2w+1 ----------
    #pragma unroll 1
    for (int rr = 0; rr < 2; ++rr) {
        const int r = w*2 + rr;
        const int q = q0 + r;

        float sv[16], ex[16];
        #pragma unroll
        for (int seg = 0; seg < 4; ++seg) {
            const float4 t = *(const float4*)&sS[r][seg*256 + lane*4];  // conflict-free
            sv[seg*4+0] = t.x; sv[seg*4+1] = t.y; sv[seg*4+2] = t.z; sv[seg*4+3] = t.w;
        }
        // unmasked row max + sum(exp)  (reference softmaxes UNmasked scores)
        float m1 = -INFINITY;
        #pragma unroll
        for (int t = 0; t < 16; ++t) m1 = fmaxf(m1, sv[t]);
        #pragma unroll
        for (int off = 32; off; off >>= 1) m1 = fmaxf(m1, __shfl_xor(m1, off, 64));
        float s1 = 0.f;
        #pragma unroll
        for (int t = 0; t < 16; ++t) { ex[t] = __expf(sv[t] - m1); s1 += ex[t]; }
        #pragma unroll
        for (int off = 32; off; off >>= 1) s1 += __shfl_xor(s1, off, 64);
        const float inv_s1 = 1.f / s1;

        // masked p + per-segment local prefix (k = seg*256 + lane*4 + j)
        float pref[16], sc[4];
        #pragma unroll
        for (int seg = 0; seg < 4; ++seg) {
            float run = 0.f;
            #pragma unroll
            for (int j = 0; j < 4; ++j) {
                const int k = seg*256 + lane*4 + j;
                const float p = (k <= q) ? ex[seg*4+j] * inv_s1 : 0.f;
                run += p;
                pref[seg*4+j] = run;
            }
            sc[seg] = run;     // local chunk sum
        }
        const float ls0 = sc[0], ls1 = sc[1], ls2 = sc[2], ls3 = sc[3];
        // 4 INDEPENDENT wave scans, interleaved for ILP
        #pragma unroll
        for (int off = 1; off < 64; off <<= 1) {
            const float t0 = __shfl_up(sc[0], off, 64);
            const float t1 = __shfl_up(sc[1], off, 64);
            const float t2 = __shfl_up(sc[2], off, 64);
            const float t3 = __shfl_up(sc[3], off, 64);
            if (lane >= off) { sc[0] += t0; sc[1] += t1; sc[2] += t2; sc[3] += t3; }
        }
        const float st0 = __shfl(sc[0], 63, 64);
        const float st1 = __shfl(sc[1], 63, 64);
        const float st2 = __shfl(sc[2], 63, 64);
        const float st3 = __shfl(sc[3], 63, 64);
        const float carry[4] = {0.f, st0, st0+st1, st0+st1+st2};
        const float excl[4]  = {sc[0]-ls0, sc[1]-ls1, sc[2]-ls2, sc[3]-ls3};
        const float total = st0 + st1 + st2 + st3;   // disttotal

        // distance decay -> masked scores
        #pragma unroll
        for (int seg = 0; seg < 4; ++seg) {
            #pragma unroll
            for (int j = 0; j < 4; ++j) {
                const int k = seg*256 + lane*4 + j;
                const int t = seg*4 + j;
                if (k <= q) {
                    const float distcum = carry[seg] + excl[seg] + pref[t];
                    const float dsc = sqrtf(fmaxf((total - distcum) * (float)(q - k), 0.f));
                    const float te  = fminf(fmaxf(__expf(dsc * gamma), 1e-5f), 1e5f);
                    sv[t] = sv[t] * te;
                } else {
                    sv[t] = -INFINITY;
                }
            }
        }

        // masked softmax
        float m2 = -INFINITY;
        #pragma unroll
        for (int t = 0; t < 16; ++t) m2 = fmaxf(m2, sv[t]);
        #pragma unroll
        for (int off = 32; off; off >>= 1) m2 = fmaxf(m2, __shfl_xor(m2, off, 64));
        float s2 = 0.f;
        #pragma unroll
        for (int t = 0; t < 16; ++t) { ex[t] = __expf(sv[t] - m2); s2 += ex[t]; }
        #pragma unroll
        for (int off = 32; off; off >>= 1) s2 += __shfl_xor(s2, off, 64);
        const float inv2 = 1.f / s2;

        #pragma unroll
        for (int seg = 0; seg < 4; ++seg) {
            float4 o;
            o.x = ex[seg*4+0]*inv2; o.y = ex[seg*4+1]*inv2;
            o.z = ex[seg*4+2]*inv2; o.w = ex[seg*4+3]*inv2;
            *(float4*)&sS[r][seg*256 + lane*4] = o;   // conflict-free
        }
    }
    __syncthreads();

    // ---------- phase 3: PV, k split 8-way across waves ----------
    const int kmax = q0 + QT;   // P==0 beyond each row's q
    float pacc[16];
    #pragma unroll
    for (int r = 0; r < 16; ++r) pacc[r] = 0.f;

    #pragma unroll 1
    for (int k4 = w*4; k4 < kmax; k4 += 32) {
        const float va = Vb[(size_t)(k4+0)*DKK + lane];   // coalesced 256B
        const float vb = Vb[(size_t)(k4+1)*DKK + lane];
        const float vc = Vb[(size_t)(k4+2)*DKK + lane];
        const float vd = Vb[(size_t)(k4+3)*DKK + lane];
        #pragma unroll
        for (int r = 0; r < 16; ++r) {
            const float4 p4 = *(const float4*)&sS[r][k4];  // b128 broadcast
            pacc[r] = fmaf(p4.x, va, pacc[r]);
            pacc[r] = fmaf(p4.y, vb, pacc[r]);
            pacc[r] = fmaf(p4.z, vc, pacc[r]);
            pacc[r] = fmaf(p4.w, vd, pacc[r]);
        }
    }
    __syncthreads();   // everyone done reading P -> sS reusable as scratch

    float* scr = &sS[0][0];
    #pragma unroll
    for (int r = 0; r < 16; ++r)
        scr[(w*16 + r)*64 + lane] = pacc[r];
    __syncthreads();

    {   // reduce 8 wave-partials; 512 thr, float2 each
        const int r = tid >> 5, c2 = (tid & 31) << 1;
        float o0 = 0.f, o1 = 0.f;
        #pragma unroll
        for (int p = 0; p < 8; ++p) {
            const float2 s = *(const float2*)&scr[(p*16 + r)*64 + c2];
            o0 += s.x; o1 += s.y;
        }
        float2 o; o.x = o0; o.y = o1;
        *(float2*)&Ao[((size_t)(b_*SS + q0 + r))*DM + h*DKK + c2] = o;
    }
}

// ============================================================
extern "C" void kernel_launch(void* const* d_in, const int* in_sizes, int n_in,
                              void* d_out, int out_size, void* d_ws, size_t ws_size,
                              hipStream_t stream)
{
    (void)in_sizes; (void)n_in; (void)out_size; (void)ws_size;

    const float* q   = (const float*)d_in[0];
    const float* k   = (const float*)d_in[1];
    const float* v   = (const float*)d_in[2];
    const float* Wq  = (const float*)d_in[3];
    const float* bq  = (const float*)d_in[4];
    const float* Wk  = (const float*)d_in[5];
    const float* bk  = (const float*)d_in[6];
    const float* Wv  = (const float*)d_in[7];
    const float* bv  = (const float*)d_in[8];
    const float* Wo  = (const float*)d_in[9];
    const float* bo  = (const float*)d_in[10];
    const float* gam = (const float*)d_in[11];
    float* out = (float*)d_out;

    float* Qh = (float*)d_ws;                       // [B,H,S,DK] 16 MiB
    float* Kh = Qh + (size_t)NTOK * DM;             // 16 MiB
    float* Vh = Kh + (size_t)NTOK * DM;             // 16 MiB
    float* Ao = Vh + (size_t)NTOK * DM;             // [B,S,DM]  16 MiB

    const dim3 ggrid(16, 64), gblk(256);
    gemm_xwT<true ><<<ggrid, gblk, 0, stream>>>(q,  Wq, bq, Qh);
    gemm_xwT<true ><<<ggrid, gblk, 0, stream>>>(k,  Wk, bk, Kh);
    gemm_xwT<true ><<<ggrid, gblk, 0, stream>>>(v,  Wv, bv, Vh);
    attn_kernel<<<dim3(4096), dim3(512), 0, stream>>>(Qh, Kh, Vh, gam, Ao);
    gemm_xwT<false><<<ggrid, gblk, 0, stream>>>(Ao, Wo, bo, out);
}

// Round 5
// 834.147 us; speedup vs baseline: 2.0295x; 2.0295x over previous
//
#include <hip/hip_runtime.h>
#include <math.h>

#define BB 4
#define SS 1024
#define DM 1024
#define HH 16
#define DKK 64
#define NTOK (BB*SS)   // 4096
#define QT 16          // q-rows per attn block

// ============================================================
// GEMM: Y = X @ W^T + bias
// X: [4096,1024] rm, W: [1024,1024] rm. 128x128 tile, 512 thr,
// 8x4 micro-tile, BK=16 (R3-proven core, ~122 us).
// OUT_MODE: 0 = flat [M,1024]
//           1 = head-split [B,H,S,DK]
//           2 = head-split TRANSPOSED [B,H,DK,S]  (for K)
// ============================================================
template<int OUT_MODE>
__global__ __launch_bounds__(512) void gemm_xwT(
    const float* __restrict__ X, const float* __restrict__ W,
    const float* __restrict__ bias, float* __restrict__ Y)
{
    __shared__ float Xs[16][132];   // [k][m]
    __shared__ float Ws[16][132];   // [k][o]

    const int tid = threadIdx.x;
    const int m0 = blockIdx.y * 128;
    const int o0 = blockIdx.x * 128;
    const int lr = tid >> 2;          // 0..127 loader row
    const int lk = (tid & 3) << 2;    // k offset 0,4,8,12
    const int tm = tid >> 5;          // 0..15 (8-row group)
    const int tn = tid & 31;          // 0..31 (4-col group)

    float acc[8][4] = {};

    for (int kt = 0; kt < 1024; kt += 16) {
        const float4 xa = *(const float4*)&X[(size_t)(m0 + lr) * 1024 + kt + lk];
        const float4 wa = *(const float4*)&W[(size_t)(o0 + lr) * 1024 + kt + lk];
        __syncthreads();   // previous iteration's LDS reads done
        Xs[lk+0][lr] = xa.x; Xs[lk+1][lr] = xa.y; Xs[lk+2][lr] = xa.z; Xs[lk+3][lr] = xa.w;
        Ws[lk+0][lr] = wa.x; Ws[lk+1][lr] = wa.y; Ws[lk+2][lr] = wa.z; Ws[lk+3][lr] = wa.w;
        __syncthreads();
        #pragma unroll
        for (int kk = 0; kk < 16; ++kk) {
            float a[8], b[4];
            *(float4*)&a[0] = *(const float4*)&Xs[kk][tm*8 + 0];  // 32-lane bcast
            *(float4*)&a[4] = *(const float4*)&Xs[kk][tm*8 + 4];
            *(float4*)&b[0] = *(const float4*)&Ws[kk][tn*4];      // contig, free
            #pragma unroll
            for (int i = 0; i < 8; ++i)
                #pragma unroll
                for (int j = 0; j < 4; ++j)
                    acc[i][j] = fmaf(a[i], b[j], acc[i][j]);
        }
    }

    const float4 b4 = *(const float4*)&bias[o0 + tn*4];
    const float bj[4] = {b4.x, b4.y, b4.z, b4.w};

    if (OUT_MODE == 2) {
        // K-transposed: Y[((b*H+h)*DK + d)*S + s], s = m contiguous per thread
        const int b_ = m0 >> 10;                 // 128 | 1024 -> constant per block
        const int s_ = (m0 & 1023) + tm*8;
        #pragma unroll
        for (int j = 0; j < 4; ++j) {
            const int o  = o0 + tn*4 + j;
            const int h_ = o >> 6, d_ = o & 63;
            float4 lo, hi;
            lo.x = acc[0][j]+bj[j]; lo.y = acc[1][j]+bj[j];
            lo.z = acc[2][j]+bj[j]; lo.w = acc[3][j]+bj[j];
            hi.x = acc[4][j]+bj[j]; hi.y = acc[5][j]+bj[j];
            hi.z = acc[6][j]+bj[j]; hi.w = acc[7][j]+bj[j];
            float* dst = &Y[(((size_t)(b_*HH + h_))*DKK + d_)*SS + s_];
            *(float4*)&dst[0] = lo;
            *(float4*)&dst[4] = hi;
        }
    } else {
        #pragma unroll
        for (int i = 0; i < 8; ++i) {
            const int m = m0 + tm*8 + i;
            float4 o;
            o.x = acc[i][0] + bj[0]; o.y = acc[i][1] + bj[1];
            o.z = acc[i][2] + bj[2]; o.w = acc[i][3] + bj[3];
            if (OUT_MODE == 1) {
                const int b_ = m >> 10, s_ = m & 1023;
                const int oc = o0 + tn*4;             // never crosses a head
                const int h_ = oc >> 6, d_ = oc & 63;
                *(float4*)&Y[(((size_t)(b_*HH + h_))*SS + s_)*DKK + d_] = o;
            } else {
                *(float4*)&Y[(size_t)m*1024 + o0 + tn*4] = o;
            }
        }
    }
}

// ============================================================
// Fused attention, 16 q-rows per block, 8 waves (512 thr).
// LDS 68KB -> 2 blocks/CU = 16 waves/CU. No VGPR cap (R4's
// forced 64-VGPR cap caused 2GB of spill traffic).
// Phase1: QK^T from TRANSPOSED K [d][s] -> coalesced loads;
//         each wave owns k and k+512 so each Q LDS-bcast
//         feeds 8 FMAs (FMA-bound, not LDS-bound).
// Phase2: wave owns 2 rows; 4 parallel 6-step scans.
// Phase3: PV k split 8-way; LDS partial reduction.
// ============================================================
__global__ __launch_bounds__(512) void attn_kernel(
    const float* __restrict__ Qh, const float* __restrict__ Kt,
    const float* __restrict__ Vh, const float* __restrict__ gammas,
    float* __restrict__ Ao)
{
    __shared__ float sS[QT][1024];   // 64 KB score rows
    __shared__ float sQ[QT][64];     // 4 KB

    const int tid  = threadIdx.x;
    const int lane = tid & 63;
    const int w    = tid >> 6;       // 0..7

    // XCD-bijective swizzle: 4096 blocks -> 512 contiguous per XCD
    const int bid = ((blockIdx.x & 7) << 9) | (blockIdx.x >> 3);
    const int bh  = bid >> 6;
    const int qt  = bid & 63;
    const int q0  = qt * QT;
    const int h   = bh & (HH - 1);
    const int b_  = bh >> 4;

    const float* Qb  = Qh + (size_t)bh * SS * DKK;
    const float* Ktb = Kt + (size_t)bh * DKK * SS;   // [64][1024]
    const float* Vb  = Vh + (size_t)bh * SS * DKK;

    const float g = gammas[h];
    const float gamma = -(fmaxf(g, 0.f) + log1pf(__expf(-fabsf(g))));

    {   // load Q tile: 512 thr x float2
        const int r = tid >> 5, c2 = (tid & 31) << 1;
        *(float2*)&sQ[r][c2] = *(const float2*)&Qb[(size_t)(q0 + r)*DKK + c2];
    }
    __syncthreads();

    // ---------- phase 1: QK^T; wave w owns k1=w*64+lane, k2=k1+512 ----------
    {
        const int k1 = w*64 + lane;           // coalesced across lanes
        float acc1[QT], acc2[QT];
        #pragma unroll
        for (int r = 0; r < QT; ++r) { acc1[r] = 0.f; acc2[r] = 0.f; }

        #pragma unroll
        for (int d0 = 0; d0 < 64; d0 += 4) {
            const float* col = &Ktb[(size_t)d0 * SS + k1];
            const float a0 = col[0*SS], a1 = col[1*SS], a2 = col[2*SS], a3 = col[3*SS];
            const float b0 = col[0*SS+512], b1 = col[1*SS+512],
                        b2 = col[2*SS+512], b3 = col[3*SS+512];
            #pragma unroll
            for (int r = 0; r < QT; ++r) {
                const float4 q4 = *(const float4*)&sQ[r][d0];   // bcast, free
                float t1 = acc1[r], t2 = acc2[r];
                t1 = fmaf(a0, q4.x, t1); t2 = fmaf(b0, q4.x, t2);
                t1 = fmaf(a1, q4.y, t1); t2 = fmaf(b1, q4.y, t2);
                t1 = fmaf(a2, q4.z, t1); t2 = fmaf(b2, q4.z, t2);
                t1 = fmaf(a3, q4.w, t1); t2 = fmaf(b3, q4.w, t2);
                acc1[r] = t1; acc2[r] = t2;
            }
        }
        #pragma unroll
        for (int r = 0; r < QT; ++r) {
            sS[r][k1]       = acc1[r] * 0.125f;   // 1/sqrt(64)
            sS[r][k1 + 512] = acc2[r] * 0.125f;
        }
    }
    __syncthreads();

    // ---------- phase 2: wave w owns rows 2w, 2w+1 ----------
    #pragma unroll 1
    for (int rr = 0; rr < 2; ++rr) {
        const int r = w*2 + rr;
        const int q = q0 + r;

        float sv[16], ex[16];
        #pragma unroll
        for (int seg = 0; seg < 4; ++seg) {
            const float4 t = *(const float4*)&sS[r][seg*256 + lane*4];  // conflict-free
            sv[seg*4+0] = t.x; sv[seg*4+1] = t.y; sv[seg*4+2] = t.z; sv[seg*4+3] = t.w;
        }
        // unmasked row max + sum(exp)  (reference softmaxes UNmasked scores)
        float m1 = -INFINITY;
        #pragma unroll
        for (int t = 0; t < 16; ++t) m1 = fmaxf(m1, sv[t]);
        #pragma unroll
        for (int off = 32; off; off >>= 1) m1 = fmaxf(m1, __shfl_xor(m1, off, 64));
        float s1 = 0.f;
        #pragma unroll
        for (int t = 0; t < 16; ++t) { ex[t] = __expf(sv[t] - m1); s1 += ex[t]; }
        #pragma unroll
        for (int off = 32; off; off >>= 1) s1 += __shfl_xor(s1, off, 64);
        const float inv_s1 = 1.f / s1;

        // masked p + per-segment local prefix (k = seg*256 + lane*4 + j)
        float pref[16], sc[4];
        #pragma unroll
        for (int seg = 0; seg < 4; ++seg) {
            float run = 0.f;
            #pragma unroll
            for (int j = 0; j < 4; ++j) {
                const int k = seg*256 + lane*4 + j;
                const float p = (k <= q) ? ex[seg*4+j] * inv_s1 : 0.f;
                run += p;
                pref[seg*4+j] = run;
            }
            sc[seg] = run;     // local chunk sum
        }
        const float ls0 = sc[0], ls1 = sc[1], ls2 = sc[2], ls3 = sc[3];
        // 4 INDEPENDENT wave scans, interleaved for ILP
        #pragma unroll
        for (int off = 1; off < 64; off <<= 1) {
            const float t0 = __shfl_up(sc[0], off, 64);
            const float t1 = __shfl_up(sc[1], off, 64);
            const float t2 = __shfl_up(sc[2], off, 64);
            const float t3 = __shfl_up(sc[3], off, 64);
            if (lane >= off) { sc[0] += t0; sc[1] += t1; sc[2] += t2; sc[3] += t3; }
        }
        const float st0 = __shfl(sc[0], 63, 64);
        const float st1 = __shfl(sc[1], 63, 64);
        const float st2 = __shfl(sc[2], 63, 64);
        const float st3 = __shfl(sc[3], 63, 64);
        const float carry[4] = {0.f, st0, st0+st1, st0+st1+st2};
        const float excl[4]  = {sc[0]-ls0, sc[1]-ls1, sc[2]-ls2, sc[3]-ls3};
        const float total = st0 + st1 + st2 + st3;   // disttotal

        // distance decay -> masked scores
        #pragma unroll
        for (int seg = 0; seg < 4; ++seg) {
            #pragma unroll
            for (int j = 0; j < 4; ++j) {
                const int k = seg*256 + lane*4 + j;
                const int t = seg*4 + j;
                if (k <= q) {
                    const float distcum = carry[seg] + excl[seg] + pref[t];
                    const float dsc = sqrtf(fmaxf((total - distcum) * (float)(q - k), 0.f));
                    const float te  = fminf(fmaxf(__expf(dsc * gamma), 1e-5f), 1e5f);
                    sv[t] = sv[t] * te;
                } else {
                    sv[t] = -INFINITY;
                }
            }
        }

        // masked softmax
        float m2 = -INFINITY;
        #pragma unroll
        for (int t = 0; t < 16; ++t) m2 = fmaxf(m2, sv[t]);
        #pragma unroll
        for (int off = 32; off; off >>= 1) m2 = fmaxf(m2, __shfl_xor(m2, off, 64));
        float s2 = 0.f;
        #pragma unroll
        for (int t = 0; t < 16; ++t) { ex[t] = __expf(sv[t] - m2); s2 += ex[t]; }
        #pragma unroll
        for (int off = 32; off; off >>= 1) s2 += __shfl_xor(s2, off, 64);
        const float inv2 = 1.f / s2;

        #pragma unroll
        for (int seg = 0; seg < 4; ++seg) {
            float4 o;
            o.x = ex[seg*4+0]*inv2; o.y = ex[seg*4+1]*inv2;
            o.z = ex[seg*4+2]*inv2; o.w = ex[seg*4+3]*inv2;
            *(float4*)&sS[r][seg*256 + lane*4] = o;   // conflict-free
        }
    }
    __syncthreads();

    // ---------- phase 3: PV, k split 8-way across waves ----------
    const int kmax = q0 + QT;   // P==0 beyond each row's q
    float pacc[16];
    #pragma unroll
    for (int r = 0; r < 16; ++r) pacc[r] = 0.f;

    #pragma unroll 1
    for (int k4 = w*4; k4 < kmax; k4 += 32) {
        const float va = Vb[(size_t)(k4+0)*DKK + lane];   // coalesced 256B
        const float vb = Vb[(size_t)(k4+1)*DKK + lane];
        const float vc = Vb[(size_t)(k4+2)*DKK + lane];
        const float vd = Vb[(size_t)(k4+3)*DKK + lane];
        #pragma unroll
        for (int r = 0; r < 16; ++r) {
            const float4 p4 = *(const float4*)&sS[r][k4];  // b128 broadcast
            pacc[r] = fmaf(p4.x, va, pacc[r]);
            pacc[r] = fmaf(p4.y, vb, pacc[r]);
            pacc[r] = fmaf(p4.z, vc, pacc[r]);
            pacc[r] = fmaf(p4.w, vd, pacc[r]);
        }
    }
    __syncthreads();   // everyone done reading P -> sS reusable as scratch

    float* scr = &sS[0][0];
    #pragma unroll
    for (int r = 0; r < 16; ++r)
        scr[(w*16 + r)*64 + lane] = pacc[r];
    __syncthreads();

    {   // reduce 8 wave-partials; 512 thr, float2 each
        const int r = tid >> 5, c2 = (tid & 31) << 1;
        float o0 = 0.f, o1 = 0.f;
        #pragma unroll
        for (int p = 0; p < 8; ++p) {
            const float2 s = *(const float2*)&scr[(p*16 + r)*64 + c2];
            o0 += s.x; o1 += s.y;
        }
        float2 o; o.x = o0; o.y = o1;
        *(float2*)&Ao[((size_t)(b_*SS + q0 + r))*DM + h*DKK + c2] = o;
    }
}

// ============================================================
extern "C" void kernel_launch(void* const* d_in, const int* in_sizes, int n_in,
                              void* d_out, int out_size, void* d_ws, size_t ws_size,
                              hipStream_t stream)
{
    (void)in_sizes; (void)n_in; (void)out_size; (void)ws_size;

    const float* q   = (const float*)d_in[0];
    const float* k   = (const float*)d_in[1];
    const float* v   = (const float*)d_in[2];
    const float* Wq  = (const float*)d_in[3];
    const float* bq  = (const float*)d_in[4];
    const float* Wk  = (const float*)d_in[5];
    const float* bk  = (const float*)d_in[6];
    const float* Wv  = (const float*)d_in[7];
    const float* bv  = (const float*)d_in[8];
    const float* Wo  = (const float*)d_in[9];
    const float* bo  = (const float*)d_in[10];
    const float* gam = (const float*)d_in[11];
    float* out = (float*)d_out;

    float* Qh = (float*)d_ws;                       // [B,H,S,DK] 16 MiB
    float* Kt = Qh + (size_t)NTOK * DM;             // [B,H,DK,S] 16 MiB
    float* Vh = Kt + (size_t)NTOK * DM;             // [B,H,S,DK] 16 MiB
    float* Ao = Vh + (size_t)NTOK * DM;             // [B,S,DM]   16 MiB

    const dim3 ggrid(8, 32), gblk(512);
    gemm_xwT<1><<<ggrid, gblk, 0, stream>>>(q,  Wq, bq, Qh);
    gemm_xwT<2><<<ggrid, gblk, 0, stream>>>(k,  Wk, bk, Kt);
    gemm_xwT<1><<<ggrid, gblk, 0, stream>>>(v,  Wv, bv, Vh);
    attn_kernel<<<dim3(4096), dim3(512), 0, stream>>>(Qh, Kt, Vh, gam, Ao);
    gemm_xwT<0><<<ggrid, gblk, 0, stream>>>(Ao, Wo, bo, out);
}

// Round 6
// 783.289 us; speedup vs baseline: 2.1612x; 1.0649x over previous
//
#include <hip/hip_runtime.h>
#include <math.h>

#define BB 4
#define SS 1024
#define DM 1024
#define HH 16
#define DKK 64
#define NTOK (BB*SS)   // 4096
#define QT 16          // q-rows per attn block

typedef __attribute__((ext_vector_type(8))) short bf16x8;
typedef __attribute__((ext_vector_type(4))) float f32x4;

// bf16 round-to-nearest-even, manual (no API-version risk)
__device__ __forceinline__ unsigned short f2bf(float x) {
    unsigned int u = __float_as_uint(x);
    u += 0x7fffu + ((u >> 16) & 1u);
    return (unsigned short)(u >> 16);
}
__device__ __forceinline__ float bf2f(unsigned short b) {
    return __uint_as_float((unsigned int)b << 16);
}

// ============================================================
// split fp32 -> (hi, lo) bf16 pair.  4 elems/thread.
// ============================================================
__global__ __launch_bounds__(256) void split_f32(
    const float* __restrict__ in, unsigned short* __restrict__ hi,
    unsigned short* __restrict__ lo, int n4)
{
    const int i = blockIdx.x * 256 + threadIdx.x;
    if (i >= n4) return;
    const float4 v = *(const float4*)&in[(size_t)i * 4];
    ushort4 hv, lv;
    hv.x = f2bf(v.x); lv.x = f2bf(v.x - bf2f(hv.x));
    hv.y = f2bf(v.y); lv.y = f2bf(v.y - bf2f(hv.y));
    hv.z = f2bf(v.z); lv.z = f2bf(v.z - bf2f(hv.z));
    hv.w = f2bf(v.w); lv.w = f2bf(v.w - bf2f(hv.w));
    *(ushort4*)&hi[(size_t)i * 4] = hv;
    *(ushort4*)&lo[(size_t)i * 4] = lv;
}

// ============================================================
// MFMA GEMM, 3-product bf16 split:
//   Y = Xh@Wh^T + Xh@Wl^T + Xl@Wh^T + bias   (error ~2^-18, << fp32 noise)
// X: [4096,1024], W: [1024,1024], both row-major bf16 hi/lo.
// Block 256 thr = 4 waves (2x2), tile 128x64, wave 64x32 =
// 4x2 frags of 16x16x32. No LDS: frags loaded direct from
// global (all L2/L3-resident), 24 MFMA : 12 b128-loads per
// K-step. Layout per m97-verified pattern: lane holds 8
// consecutive k of row (lane&15), k-group (lane>>4)*8;
// C/D: col=lane&15, row=(lane>>4)*4+reg.
// OUT_MODE: 0 flat [M,1024]; 1 head-split [B,H,S,DK];
//           2 head-split transposed [B,H,DK,S] (for K).
// ============================================================
template<int OUT_MODE>
__global__ __launch_bounds__(256) void gemm_bf16x3(
    const unsigned short* __restrict__ Xh, const unsigned short* __restrict__ Xl,
    const unsigned short* __restrict__ Wh, const unsigned short* __restrict__ Wl,
    const float* __restrict__ bias, float* __restrict__ Y)
{
    const int tid  = threadIdx.x;
    const int lane = tid & 63;
    const int w    = tid >> 6;        // 0..3
    const int wr   = w >> 1, wc = w & 1;
    const int r16  = lane & 15, kg = lane >> 4;

    // XCD swizzle over 512 blocks: round-robin-dispatched blocks on one
    // XCD get contiguous swz -> share A-panels in that XCD's L2.
    const int lin = blockIdx.y * 16 + blockIdx.x;
    const int swz = (lin & 7) * 64 + (lin >> 3);
    const int mt  = swz >> 4, nt = swz & 15;

    const int mbase = mt * 128 + wr * 64;
    const int obase = nt * 64  + wc * 32;

    const size_t arow = (size_t)(mbase + r16) * 1024 + kg * 8;
    const size_t brow = (size_t)(obase + r16) * 1024 + kg * 8;

    f32x4 acc[4][2];
    const f32x4 zero = {0.f, 0.f, 0.f, 0.f};
    #pragma unroll
    for (int i = 0; i < 4; ++i)
        #pragma unroll
        for (int j = 0; j < 2; ++j) acc[i][j] = zero;

    #pragma unroll 1
    for (int kt = 0; kt < 1024; kt += 32) {
        bf16x8 ah[4], al[4], bh[2], bl[2];
        #pragma unroll
        for (int i = 0; i < 4; ++i) {
            ah[i] = *(const bf16x8*)&Xh[arow + (size_t)i * 16 * 1024 + kt];
            al[i] = *(const bf16x8*)&Xl[arow + (size_t)i * 16 * 1024 + kt];
        }
        #pragma unroll
        for (int j = 0; j < 2; ++j) {
            bh[j] = *(const bf16x8*)&Wh[brow + (size_t)j * 16 * 1024 + kt];
            bl[j] = *(const bf16x8*)&Wl[brow + (size_t)j * 16 * 1024 + kt];
        }
        #pragma unroll
        for (int i = 0; i < 4; ++i)
            #pragma unroll
            for (int j = 0; j < 2; ++j) {
                acc[i][j] = __builtin_amdgcn_mfma_f32_16x16x32_bf16(ah[i], bh[j], acc[i][j], 0, 0, 0);
                acc[i][j] = __builtin_amdgcn_mfma_f32_16x16x32_bf16(ah[i], bl[j], acc[i][j], 0, 0, 0);
                acc[i][j] = __builtin_amdgcn_mfma_f32_16x16x32_bf16(al[i], bh[j], acc[i][j], 0, 0, 0);
            }
    }

    #pragma unroll
    for (int i = 0; i < 4; ++i) {
        const int mrow0 = mbase + i * 16 + kg * 4;   // +reg (4 consecutive rows)
        #pragma unroll
        for (int j = 0; j < 2; ++j) {
            const int col = obase + j * 16 + r16;
            const float bv = bias[col];
            if (OUT_MODE == 2) {
                // [B,H,DK,S]: 4 consecutive s -> float4 store
                const int b_ = mrow0 >> 10, s_ = mrow0 & 1023;
                const int h_ = col >> 6, d_ = col & 63;
                float4 o;
                o.x = acc[i][j][0] + bv; o.y = acc[i][j][1] + bv;
                o.z = acc[i][j][2] + bv; o.w = acc[i][j][3] + bv;
                *(float4*)&Y[(((size_t)(b_ * HH + h_)) * DKK + d_) * SS + s_] = o;
            } else {
                #pragma unroll
                for (int rg = 0; rg < 4; ++rg) {
                    const int m = mrow0 + rg;
                    const float val = acc[i][j][rg] + bv;
                    if (OUT_MODE == 1) {
                        const int b_ = m >> 10, s_ = m & 1023;
                        const int h_ = col >> 6, d_ = col & 63;
                        Y[(((size_t)(b_ * HH + h_)) * SS + s_) * DKK + d_] = val;
                    } else {
                        Y[(size_t)m * 1024 + col] = val;
                    }
                }
            }
        }
    }
}

// ============================================================
// Fused attention (R5-verified: VALUBusy ~100%, 0 conflicts).
// Only change: epilogue writes the hi/lo bf16 split of the
// concat directly (feeds the final MFMA GEMM, saves a pass).
// ============================================================
__global__ __launch_bounds__(512) void attn_kernel(
    const float* __restrict__ Qh, const float* __restrict__ Kt,
    const float* __restrict__ Vh, const float* __restrict__ gammas,
    unsigned short* __restrict__ AoH, unsigned short* __restrict__ AoL)
{
    __shared__ float sS[QT][1024];   // 64 KB score rows
    __shared__ float sQ[QT][64];     // 4 KB

    const int tid  = threadIdx.x;
    const int lane = tid & 63;
    const int w    = tid >> 6;       // 0..7

    const int bid = ((blockIdx.x & 7) << 9) | (blockIdx.x >> 3);
    const int bh  = bid >> 6;
    const int qt  = bid & 63;
    const int q0  = qt * QT;
    const int h   = bh & (HH - 1);
    const int b_  = bh >> 4;

    const float* Qb  = Qh + (size_t)bh * SS * DKK;
    const float* Ktb = Kt + (size_t)bh * DKK * SS;   // [64][1024]
    const float* Vb  = Vh + (size_t)bh * SS * DKK;

    const float g = gammas[h];
    const float gamma = -(fmaxf(g, 0.f) + log1pf(__expf(-fabsf(g))));

    {   // load Q tile: 512 thr x float2
        const int r = tid >> 5, c2 = (tid & 31) << 1;
        *(float2*)&sQ[r][c2] = *(const float2*)&Qb[(size_t)(q0 + r)*DKK + c2];
    }
    __syncthreads();

    // ---------- phase 1: QK^T; wave w owns k1=w*64+lane, k2=k1+512 ----------
    {
        const int k1 = w*64 + lane;           // coalesced across lanes
        float acc1[QT], acc2[QT];
        #pragma unroll
        for (int r = 0; r < QT; ++r) { acc1[r] = 0.f; acc2[r] = 0.f; }

        #pragma unroll
        for (int d0 = 0; d0 < 64; d0 += 4) {
            const float* col = &Ktb[(size_t)d0 * SS + k1];
            const float a0 = col[0*SS], a1 = col[1*SS], a2 = col[2*SS], a3 = col[3*SS];
            const float b0 = col[0*SS+512], b1 = col[1*SS+512],
                        b2 = col[2*SS+512], b3 = col[3*SS+512];
            #pragma unroll
            for (int r = 0; r < QT; ++r) {
                const float4 q4 = *(const float4*)&sQ[r][d0];   // bcast, free
                float t1 = acc1[r], t2 = acc2[r];
                t1 = fmaf(a0, q4.x, t1); t2 = fmaf(b0, q4.x, t2);
                t1 = fmaf(a1, q4.y, t1); t2 = fmaf(b1, q4.y, t2);
                t1 = fmaf(a2, q4.z, t1); t2 = fmaf(b2, q4.z, t2);
                t1 = fmaf(a3, q4.w, t1); t2 = fmaf(b3, q4.w, t2);
                acc1[r] = t1; acc2[r] = t2;
            }
        }
        #pragma unroll
        for (int r = 0; r < QT; ++r) {
            sS[r][k1]       = acc1[r] * 0.125f;   // 1/sqrt(64)
            sS[r][k1 + 512] = acc2[r] * 0.125f;
        }
    }
    __syncthreads();

    // ---------- phase 2: wave w owns rows 2w, 2w+1 ----------
    #pragma unroll 1
    for (int rr = 0; rr < 2; ++rr) {
        const int r = w*2 + rr;
        const int q = q0 + r;

        float sv[16], ex[16];
        #pragma unroll
        for (int seg = 0; seg < 4; ++seg) {
            const float4 t = *(const float4*)&sS[r][seg*256 + lane*4];  // conflict-free
            sv[seg*4+0] = t.x; sv[seg*4+1] = t.y; sv[seg*4+2] = t.z; sv[seg*4+3] = t.w;
        }
        float m1 = -INFINITY;
        #pragma unroll
        for (int t = 0; t < 16; ++t) m1 = fmaxf(m1, sv[t]);
        #pragma unroll
        for (int off = 32; off; off >>= 1) m1 = fmaxf(m1, __shfl_xor(m1, off, 64));
        float s1 = 0.f;
        #pragma unroll
        for (int t = 0; t < 16; ++t) { ex[t] = __expf(sv[t] - m1); s1 += ex[t]; }
        #pragma unroll
        for (int off = 32; off; off >>= 1) s1 += __shfl_xor(s1, off, 64);
        const float inv_s1 = 1.f / s1;

        float pref[16], sc[4];
        #pragma unroll
        for (int seg = 0; seg < 4; ++seg) {
            float run = 0.f;
            #pragma unroll
            for (int j = 0; j < 4; ++j) {
                const int k = seg*256 + lane*4 + j;
                const float p = (k <= q) ? ex[seg*4+j] * inv_s1 : 0.f;
                run += p;
                pref[seg*4+j] = run;
            }
            sc[seg] = run;
        }
        const float ls0 = sc[0], ls1 = sc[1], ls2 = sc[2], ls3 = sc[3];
        #pragma unroll
        for (int off = 1; off < 64; off <<= 1) {
            const float t0 = __shfl_up(sc[0], off, 64);
            const float t1 = __shfl_up(sc[1], off, 64);
            const float t2 = __shfl_up(sc[2], off, 64);
            const float t3 = __shfl_up(sc[3], off, 64);
            if (lane >= off) { sc[0] += t0; sc[1] += t1; sc[2] += t2; sc[3] += t3; }
        }
        const float st0 = __shfl(sc[0], 63, 64);
        const float st1 = __shfl(sc[1], 63, 64);
        const float st2 = __shfl(sc[2], 63, 64);
        const float st3 = __shfl(sc[3], 63, 64);
        const float carry[4] = {0.f, st0, st0+st1, st0+st1+st2};
        const float excl[4]  = {sc[0]-ls0, sc[1]-ls1, sc[2]-ls2, sc[3]-ls3};
        const float total = st0 + st1 + st2 + st3;

        #pragma unroll
        for (int seg = 0; seg < 4; ++seg) {
            #pragma unroll
            for (int j = 0; j < 4; ++j) {
                const int k = seg*256 + lane*4 + j;
                const int t = seg*4 + j;
                if (k <= q) {
                    const float distcum = carry[seg] + excl[seg] + pref[t];
                    const float dsc = sqrtf(fmaxf((total - distcum) * (float)(q - k), 0.f));
                    const float te  = fminf(fmaxf(__expf(dsc * gamma), 1e-5f), 1e5f);
                    sv[t] = sv[t] * te;
                } else {
                    sv[t] = -INFINITY;
                }
            }
        }

        float m2 = -INFINITY;
        #pragma unroll
        for (int t = 0; t < 16; ++t) m2 = fmaxf(m2, sv[t]);
        #pragma unroll
        for (int off = 32; off; off >>= 1) m2 = fmaxf(m2, __shfl_xor(m2, off, 64));
        float s2 = 0.f;
        #pragma unroll
        for (int t = 0; t < 16; ++t) { ex[t] = __expf(sv[t] - m2); s2 += ex[t]; }
        #pragma unroll
        for (int off = 32; off; off >>= 1) s2 += __shfl_xor(s2, off, 64);
        const float inv2 = 1.f / s2;

        #pragma unroll
        for (int seg = 0; seg < 4; ++seg) {
            float4 o;
            o.x = ex[seg*4+0]*inv2; o.y = ex[seg*4+1]*inv2;
            o.z = ex[seg*4+2]*inv2; o.w = ex[seg*4+3]*inv2;
            *(float4*)&sS[r][seg*256 + lane*4] = o;
        }
    }
    __syncthreads();

    // ---------- phase 3: PV, k split 8-way across waves ----------
    const int kmax = q0 + QT;
    float pacc[16];
    #pragma unroll
    for (int r = 0; r < 16; ++r) pacc[r] = 0.f;

    #pragma unroll 1
    for (int k4 = w*4; k4 < kmax; k4 += 32) {
        const float va = Vb[(size_t)(k4+0)*DKK + lane];
        const float vb = Vb[(size_t)(k4+1)*DKK + lane];
        const float vc = Vb[(size_t)(k4+2)*DKK + lane];
        const float vd = Vb[(size_t)(k4+3)*DKK + lane];
        #pragma unroll
        for (int r = 0; r < 16; ++r) {
            const float4 p4 = *(const float4*)&sS[r][k4];
            pacc[r] = fmaf(p4.x, va, pacc[r]);
            pacc[r] = fmaf(p4.y, vb, pacc[r]);
            pacc[r] = fmaf(p4.z, vc, pacc[r]);
            pacc[r] = fmaf(p4.w, vd, pacc[r]);
        }
    }
    __syncthreads();

    float* scr = &sS[0][0];
    #pragma unroll
    for (int r = 0; r < 16; ++r)
        scr[(w*16 + r)*64 + lane] = pacc[r];
    __syncthreads();

    {   // reduce 8 wave-partials; write hi/lo bf16 split, concat layout
        const int r = tid >> 5, c2 = (tid & 31) << 1;
        float o0 = 0.f, o1 = 0.f;
        #pragma unroll
        for (int p = 0; p < 8; ++p) {
            const float2 s = *(const float2*)&scr[(p*16 + r)*64 + c2];
            o0 += s.x; o1 += s.y;
        }
        const size_t idx = ((size_t)(b_*SS + q0 + r))*DM + h*DKK + c2;
        ushort2 hv, lv;
        hv.x = f2bf(o0); lv.x = f2bf(o0 - bf2f(hv.x));
        hv.y = f2bf(o1); lv.y = f2bf(o1 - bf2f(hv.y));
        *(ushort2*)&AoH[idx] = hv;
        *(ushort2*)&AoL[idx] = lv;
    }
}

// ============================================================
extern "C" void kernel_launch(void* const* d_in, const int* in_sizes, int n_in,
                              void* d_out, int out_size, void* d_ws, size_t ws_size,
                              hipStream_t stream)
{
    (void)in_sizes; (void)n_in; (void)out_size; (void)ws_size;

    const float* q   = (const float*)d_in[0];
    const float* k   = (const float*)d_in[1];
    const float* v   = (const float*)d_in[2];
    const float* Wq  = (const float*)d_in[3];
    const float* bq  = (const float*)d_in[4];
    const float* Wk  = (const float*)d_in[5];
    const float* bk  = (const float*)d_in[6];
    const float* Wv  = (const float*)d_in[7];
    const float* bv  = (const float*)d_in[8];
    const float* Wo  = (const float*)d_in[9];
    const float* bo  = (const float*)d_in[10];
    const float* gam = (const float*)d_in[11];
    float* out = (float*)d_out;

    const size_t NE = (size_t)NTOK * DM;            // 4M elems
    float* Qh = (float*)d_ws;                       // fp32 16.8MB
    float* Kt = Qh + NE;                            // fp32 16.8MB [B,H,DK,S]
    float* Vh = Kt + NE;                            // fp32 16.8MB
    unsigned short* xh = (unsigned short*)(Vh + NE);// bf16 8.4MB (X / Ao split)
    unsigned short* xl = xh + NE;                   // bf16 8.4MB
    unsigned short* wh = xl + NE;                   // bf16 2.1MB (W split)
    unsigned short* wl = wh + (size_t)DM * DM;      // bf16 2.1MB

    const dim3 ggrid(16, 32), gblk(256);            // 512 blocks

    split_f32<<<4096, 256, 0, stream>>>(q,  xh, xl, 1048576);
    split_f32<<<1024, 256, 0, stream>>>(Wq, wh, wl, 262144);
    gemm_bf16x3<1><<<ggrid, gblk, 0, stream>>>(xh, xl, wh, wl, bq, Qh);

    split_f32<<<4096, 256, 0, stream>>>(k,  xh, xl, 1048576);
    split_f32<<<1024, 256, 0, stream>>>(Wk, wh, wl, 262144);
    gemm_bf16x3<2><<<ggrid, gblk, 0, stream>>>(xh, xl, wh, wl, bk, Kt);

    split_f32<<<4096, 256, 0, stream>>>(v,  xh, xl, 1048576);
    split_f32<<<1024, 256, 0, stream>>>(Wv, wh, wl, 262144);
    gemm_bf16x3<1><<<ggrid, gblk, 0, stream>>>(xh, xl, wh, wl, bv, Vh);

    attn_kernel<<<dim3(4096), dim3(512), 0, stream>>>(Qh, Kt, Vh, gam, xh, xl);

    split_f32<<<1024, 256, 0, stream>>>(Wo, wh, wl, 262144);
    gemm_bf16x3<0><<<ggrid, gblk, 0, stream>>>(xh, xl, wh, wl, bo, out);
}

// Round 7
// 754.772 us; speedup vs baseline: 2.2429x; 1.0378x over previous
//
#include <hip/hip_runtime.h>
#include <math.h>

#define BB 4
#define SS 1024
#define DM 1024
#define HH 16
#define DKK 64
#define NTOK (BB*SS)   // 4096
#define QT 16          // q-rows per attn block

typedef __attribute__((ext_vector_type(8))) short bf16x8;
typedef __attribute__((ext_vector_type(4))) float f32x4;
typedef unsigned short u16;

// bf16 round-to-nearest-even, manual
__device__ __forceinline__ u16 f2bf(float x) {
    unsigned int u = __float_as_uint(x);
    u += 0x7fffu + ((u >> 16) & 1u);
    return (u16)(u >> 16);
}
__device__ __forceinline__ float bf2f(u16 b) {
    return __uint_as_float((unsigned int)b << 16);
}

__device__ __forceinline__ void split4(const float4 v, ushort4* hv, ushort4* lv) {
    hv->x = f2bf(v.x); lv->x = f2bf(v.x - bf2f(hv->x));
    hv->y = f2bf(v.y); lv->y = f2bf(v.y - bf2f(hv->y));
    hv->z = f2bf(v.z); lv->z = f2bf(v.z - bf2f(hv->z));
    hv->w = f2bf(v.w); lv->w = f2bf(v.w - bf2f(hv->w));
}

// ============================================================
// split q,k,v (3 x 4M elems) in one launch: 12288 blocks.
// ============================================================
__global__ __launch_bounds__(256) void split_x3(
    const float* __restrict__ a, const float* __restrict__ b, const float* __restrict__ c,
    u16* __restrict__ ah, u16* __restrict__ al,
    u16* __restrict__ bh, u16* __restrict__ bl,
    u16* __restrict__ ch, u16* __restrict__ cl)
{
    const int t = blockIdx.x >> 12;                       // 4096 blocks/tensor
    const int i = ((blockIdx.x & 4095) << 8) + threadIdx.x;  // float4 idx < 1048576
    const float* in = (t == 0) ? a : (t == 1) ? b : c;
    u16* oh = (t == 0) ? ah : (t == 1) ? bh : ch;
    u16* ol = (t == 0) ? al : (t == 1) ? bl : cl;
    const float4 v = *(const float4*)&in[(size_t)i * 4];
    ushort4 hv, lv;
    split4(v, &hv, &lv);
    *(ushort4*)&oh[(size_t)i * 4] = hv;
    *(ushort4*)&ol[(size_t)i * 4] = lv;
}

// ============================================================
// split Wq,Wk,Wv,Wo (4 x 1M elems) in one launch: 4096 blocks.
// Outputs are consecutive: w[8] = {qh,ql,kh,kl,vh,vl,oh,ol}
// laid out contiguously from base (each 1M u16).
// ============================================================
__global__ __launch_bounds__(256) void split_w4(
    const float* __restrict__ wq, const float* __restrict__ wk,
    const float* __restrict__ wv, const float* __restrict__ wo,
    u16* __restrict__ base)
{
    const int t = blockIdx.x >> 10;                       // 1024 blocks/tensor
    const int i = ((blockIdx.x & 1023) << 8) + threadIdx.x;  // float4 idx < 262144
    const float* in = (t == 0) ? wq : (t == 1) ? wk : (t == 2) ? wv : wo;
    u16* oh = base + (size_t)(2 * t)     * 1048576;
    u16* ol = base + (size_t)(2 * t + 1) * 1048576;
    const float4 v = *(const float4*)&in[(size_t)i * 4];
    ushort4 hv, lv;
    split4(v, &hv, &lv);
    *(ushort4*)&oh[(size_t)i * 4] = hv;
    *(ushort4*)&ol[(size_t)i * 4] = lv;
}

// ============================================================
// MFMA GEMM core (3-product bf16 split), R6-verified inner loop.
// tile 128x64, 4 waves (2x2), wave 64x32 = 4x2 frags 16x16x32,
// no LDS (frags direct from global, L2-resident).
// ============================================================
__device__ __forceinline__ void gemm_core(
    const u16* __restrict__ Xh, const u16* __restrict__ Xl,
    const u16* __restrict__ Wh, const u16* __restrict__ Wl,
    const float* __restrict__ bias, float* __restrict__ Y,
    int lin, int mode /*0 flat, 1 head-split, 2 head-split-T*/)
{
    const int tid  = threadIdx.x;
    const int lane = tid & 63;
    const int w    = tid >> 6;
    const int wr   = w >> 1, wc = w & 1;
    const int r16  = lane & 15, kg = lane >> 4;

    // XCD swizzle over 512 blocks
    const int swz = (lin & 7) * 64 + (lin >> 3);
    const int mt  = swz >> 4, nt = swz & 15;

    const int mbase = mt * 128 + wr * 64;
    const int obase = nt * 64  + wc * 32;

    const size_t arow = (size_t)(mbase + r16) * 1024 + kg * 8;
    const size_t brow = (size_t)(obase + r16) * 1024 + kg * 8;

    f32x4 acc[4][2];
    const f32x4 zero = {0.f, 0.f, 0.f, 0.f};
    #pragma unroll
    for (int i = 0; i < 4; ++i)
        #pragma unroll
        for (int j = 0; j < 2; ++j) acc[i][j] = zero;

    #pragma unroll 1
    for (int kt = 0; kt < 1024; kt += 32) {
        bf16x8 ah[4], al[4], bh[2], bl[2];
        #pragma unroll
        for (int i = 0; i < 4; ++i) {
            ah[i] = *(const bf16x8*)&Xh[arow + (size_t)i * 16 * 1024 + kt];
            al[i] = *(const bf16x8*)&Xl[arow + (size_t)i * 16 * 1024 + kt];
        }
        #pragma unroll
        for (int j = 0; j < 2; ++j) {
            bh[j] = *(const bf16x8*)&Wh[brow + (size_t)j * 16 * 1024 + kt];
            bl[j] = *(const bf16x8*)&Wl[brow + (size_t)j * 16 * 1024 + kt];
        }
        #pragma unroll
        for (int i = 0; i < 4; ++i)
            #pragma unroll
            for (int j = 0; j < 2; ++j) {
                acc[i][j] = __builtin_amdgcn_mfma_f32_16x16x32_bf16(ah[i], bh[j], acc[i][j], 0, 0, 0);
                acc[i][j] = __builtin_amdgcn_mfma_f32_16x16x32_bf16(ah[i], bl[j], acc[i][j], 0, 0, 0);
                acc[i][j] = __builtin_amdgcn_mfma_f32_16x16x32_bf16(al[i], bh[j], acc[i][j], 0, 0, 0);
            }
    }

    #pragma unroll
    for (int i = 0; i < 4; ++i) {
        const int mrow0 = mbase + i * 16 + kg * 4;   // 4 consecutive m rows
        #pragma unroll
        for (int j = 0; j < 2; ++j) {
            const int col = obase + j * 16 + r16;
            const float bv = bias[col];
            if (mode == 2) {
                const int b_ = mrow0 >> 10, s_ = mrow0 & 1023;
                const int h_ = col >> 6, d_ = col & 63;
                float4 o;
                o.x = acc[i][j][0] + bv; o.y = acc[i][j][1] + bv;
                o.z = acc[i][j][2] + bv; o.w = acc[i][j][3] + bv;
                *(float4*)&Y[(((size_t)(b_ * HH + h_)) * DKK + d_) * SS + s_] = o;
            } else if (mode == 1) {
                #pragma unroll
                for (int rg = 0; rg < 4; ++rg) {
                    const int m = mrow0 + rg;
                    const int b_ = m >> 10, s_ = m & 1023;
                    const int h_ = col >> 6, d_ = col & 63;
                    Y[(((size_t)(b_ * HH + h_)) * SS + s_) * DKK + d_] = acc[i][j][rg] + bv;
                }
            } else {
                #pragma unroll
                for (int rg = 0; rg < 4; ++rg)
                    Y[(size_t)(mrow0 + rg) * 1024 + col] = acc[i][j][rg] + bv;
            }
        }
    }
}

// Batched Q/K/V projection: 1536 blocks (3 x 512) -> 6 blocks/CU.
__global__ __launch_bounds__(256) void gemm_qkv(
    const u16* __restrict__ qh, const u16* __restrict__ ql,
    const u16* __restrict__ kh, const u16* __restrict__ kl,
    const u16* __restrict__ vh, const u16* __restrict__ vl,
    const u16* __restrict__ wbase,
    const float* __restrict__ bq, const float* __restrict__ bk, const float* __restrict__ bv,
    float* __restrict__ Qh, float* __restrict__ Kt, float* __restrict__ Vh)
{
    const int z   = blockIdx.x >> 9;     // 0,1,2
    const int lin = blockIdx.x & 511;
    const u16 *Xh, *Xl, *Wh, *Wl; const float* bias; float* Y; int mode;
    if (z == 0)      { Xh=qh; Xl=ql; Wh=wbase;           Wl=wbase+1048576;   bias=bq; Y=Qh; mode=1; }
    else if (z == 1) { Xh=kh; Xl=kl; Wh=wbase+2*1048576; Wl=wbase+3*1048576; bias=bk; Y=Kt; mode=2; }
    else             { Xh=vh; Xl=vl; Wh=wbase+4*1048576; Wl=wbase+5*1048576; bias=bv; Y=Vh; mode=1; }
    gemm_core(Xh, Xl, Wh, Wl, bias, Y, lin, mode);
}

// Output projection (flat out), 512 blocks.
__global__ __launch_bounds__(256) void gemm_out(
    const u16* __restrict__ Xh, const u16* __restrict__ Xl,
    const u16* __restrict__ wbase, const float* __restrict__ bias,
    float* __restrict__ Y)
{
    gemm_core(Xh, Xl, wbase + 6*1048576, wbase + 7*1048576, bias, Y, blockIdx.x, 0);
}

// ============================================================
// Fused attention (R5/R6-verified: 330us, VALUBusy ~100%, 0
// conflicts). Epilogue writes hi/lo bf16 split of concat.
// ============================================================
__global__ __launch_bounds__(512) void attn_kernel(
    const float* __restrict__ Qh, const float* __restrict__ Kt,
    const float* __restrict__ Vh, const float* __restrict__ gammas,
    u16* __restrict__ AoH, u16* __restrict__ AoL)
{
    __shared__ float sS[QT][1024];   // 64 KB score rows
    __shared__ float sQ[QT][64];     // 4 KB

    const int tid  = threadIdx.x;
    const int lane = tid & 63;
    const int w    = tid >> 6;       // 0..7

    const int bid = ((blockIdx.x & 7) << 9) | (blockIdx.x >> 3);
    const int bh  = bid >> 6;
    const int qt  = bid & 63;
    const int q0  = qt * QT;
    const int h   = bh & (HH - 1);
    const int b_  = bh >> 4;

    const float* Qb  = Qh + (size_t)bh * SS * DKK;
    const float* Ktb = Kt + (size_t)bh * DKK * SS;   // [64][1024]
    const float* Vb  = Vh + (size_t)bh * SS * DKK;

    const float g = gammas[h];
    const float gamma = -(fmaxf(g, 0.f) + log1pf(__expf(-fabsf(g))));

    {   // load Q tile: 512 thr x float2
        const int r = tid >> 5, c2 = (tid & 31) << 1;
        *(float2*)&sQ[r][c2] = *(const float2*)&Qb[(size_t)(q0 + r)*DKK + c2];
    }
    __syncthreads();

    // ---------- phase 1: QK^T; wave w owns k1=w*64+lane, k2=k1+512 ----------
    {
        const int k1 = w*64 + lane;           // coalesced across lanes
        float acc1[QT], acc2[QT];
        #pragma unroll
        for (int r = 0; r < QT; ++r) { acc1[r] = 0.f; acc2[r] = 0.f; }

        #pragma unroll
        for (int d0 = 0; d0 < 64; d0 += 4) {
            const float* col = &Ktb[(size_t)d0 * SS + k1];
            const float a0 = col[0*SS], a1 = col[1*SS], a2 = col[2*SS], a3 = col[3*SS];
            const float b0 = col[0*SS+512], b1 = col[1*SS+512],
                        b2 = col[2*SS+512], b3 = col[3*SS+512];
            #pragma unroll
            for (int r = 0; r < QT; ++r) {
                const float4 q4 = *(const float4*)&sQ[r][d0];   // bcast, free
                float t1 = acc1[r], t2 = acc2[r];
                t1 = fmaf(a0, q4.x, t1); t2 = fmaf(b0, q4.x, t2);
                t1 = fmaf(a1, q4.y, t1); t2 = fmaf(b1, q4.y, t2);
                t1 = fmaf(a2, q4.z, t1); t2 = fmaf(b2, q4.z, t2);
                t1 = fmaf(a3, q4.w, t1); t2 = fmaf(b3, q4.w, t2);
                acc1[r] = t1; acc2[r] = t2;
            }
        }
        #pragma unroll
        for (int r = 0; r < QT; ++r) {
            sS[r][k1]       = acc1[r] * 0.125f;   // 1/sqrt(64)
            sS[r][k1 + 512] = acc2[r] * 0.125f;
        }
    }
    __syncthreads();

    // ---------- phase 2: wave w owns rows 2w, 2w+1 ----------
    #pragma unroll 1
    for (int rr = 0; rr < 2; ++rr) {
        const int r = w*2 + rr;
        const int q = q0 + r;

        float sv[16], ex[16];
        #pragma unroll
        for (int seg = 0; seg < 4; ++seg) {
            const float4 t = *(const float4*)&sS[r][seg*256 + lane*4];  // conflict-free
            sv[seg*4+0] = t.x; sv[seg*4+1] = t.y; sv[seg*4+2] = t.z; sv[seg*4+3] = t.w;
        }
        float m1 = -INFINITY;
        #pragma unroll
        for (int t = 0; t < 16; ++t) m1 = fmaxf(m1, sv[t]);
        #pragma unroll
        for (int off = 32; off; off >>= 1) m1 = fmaxf(m1, __shfl_xor(m1, off, 64));
        float s1 = 0.f;
        #pragma unroll
        for (int t = 0; t < 16; ++t) { ex[t] = __expf(sv[t] - m1); s1 += ex[t]; }
        #pragma unroll
        for (int off = 32; off; off >>= 1) s1 += __shfl_xor(s1, off, 64);
        const float inv_s1 = 1.f / s1;

        float pref[16], sc[4];
        #pragma unroll
        for (int seg = 0; seg < 4; ++seg) {
            float run = 0.f;
            #pragma unroll
            for (int j = 0; j < 4; ++j) {
                const int k = seg*256 + lane*4 + j;
                const float p = (k <= q) ? ex[seg*4+j] * inv_s1 : 0.f;
                run += p;
                pref[seg*4+j] = run;
            }
            sc[seg] = run;
        }
        const float ls0 = sc[0], ls1 = sc[1], ls2 = sc[2], ls3 = sc[3];
        #pragma unroll
        for (int off = 1; off < 64; off <<= 1) {
            const float t0 = __shfl_up(sc[0], off, 64);
            const float t1 = __shfl_up(sc[1], off, 64);
            const float t2 = __shfl_up(sc[2], off, 64);
            const float t3 = __shfl_up(sc[3], off, 64);
            if (lane >= off) { sc[0] += t0; sc[1] += t1; sc[2] += t2; sc[3] += t3; }
        }
        const float st0 = __shfl(sc[0], 63, 64);
        const float st1 = __shfl(sc[1], 63, 64);
        const float st2 = __shfl(sc[2], 63, 64);
        const float st3 = __shfl(sc[3], 63, 64);
        const float carry[4] = {0.f, st0, st0+st1, st0+st1+st2};
        const float excl[4]  = {sc[0]-ls0, sc[1]-ls1, sc[2]-ls2, sc[3]-ls3};
        const float total = st0 + st1 + st2 + st3;

        #pragma unroll
        for (int seg = 0; seg < 4; ++seg) {
            #pragma unroll
            for (int j = 0; j < 4; ++j) {
                const int k = seg*256 + lane*4 + j;
                const int t = seg*4 + j;
                if (k <= q) {
                    const float distcum = carry[seg] + excl[seg] + pref[t];
                    const float dsc = sqrtf(fmaxf((total - distcum) * (float)(q - k), 0.f));
                    const float te  = fminf(fmaxf(__expf(dsc * gamma), 1e-5f), 1e5f);
                    sv[t] = sv[t] * te;
                } else {
                    sv[t] = -INFINITY;
                }
            }
        }

        float m2 = -INFINITY;
        #pragma unroll
        for (int t = 0; t < 16; ++t) m2 = fmaxf(m2, sv[t]);
        #pragma unroll
        for (int off = 32; off; off >>= 1) m2 = fmaxf(m2, __shfl_xor(m2, off, 64));
        float s2 = 0.f;
        #pragma unroll
        for (int t = 0; t < 16; ++t) { ex[t] = __expf(sv[t] - m2); s2 += ex[t]; }
        #pragma unroll
        for (int off = 32; off; off >>= 1) s2 += __shfl_xor(s2, off, 64);
        const float inv2 = 1.f / s2;

        #pragma unroll
        for (int seg = 0; seg < 4; ++seg) {
            float4 o;
            o.x = ex[seg*4+0]*inv2; o.y = ex[seg*4+1]*inv2;
            o.z = ex[seg*4+2]*inv2; o.w = ex[seg*4+3]*inv2;
            *(float4*)&sS[r][seg*256 + lane*4] = o;
        }
    }
    __syncthreads();

    // ---------- phase 3: PV, k split 8-way across waves ----------
    const int kmax = q0 + QT;
    float pacc[16];
    #pragma unroll
    for (int r = 0; r < 16; ++r) pacc[r] = 0.f;

    #pragma unroll 1
    for (int k4 = w*4; k4 < kmax; k4 += 32) {
        const float va = Vb[(size_t)(k4+0)*DKK + lane];
        const float vb = Vb[(size_t)(k4+1)*DKK + lane];
        const float vc = Vb[(size_t)(k4+2)*DKK + lane];
        const float vd = Vb[(size_t)(k4+3)*DKK + lane];
        #pragma unroll
        for (int r = 0; r < 16; ++r) {
            const float4 p4 = *(const float4*)&sS[r][k4];
            pacc[r] = fmaf(p4.x, va, pacc[r]);
            pacc[r] = fmaf(p4.y, vb, pacc[r]);
            pacc[r] = fmaf(p4.z, vc, pacc[r]);
            pacc[r] = fmaf(p4.w, vd, pacc[r]);
        }
    }
    __syncthreads();

    float* scr = &sS[0][0];
    #pragma unroll
    for (int r = 0; r < 16; ++r)
        scr[(w*16 + r)*64 + lane] = pacc[r];
    __syncthreads();

    {   // reduce 8 wave-partials; write hi/lo bf16 split, concat layout
        const int r = tid >> 5, c2 = (tid & 31) << 1;
        float o0 = 0.f, o1 = 0.f;
        #pragma unroll
        for (int p = 0; p < 8; ++p) {
            const float2 s = *(const float2*)&scr[(p*16 + r)*64 + c2];
            o0 += s.x; o1 += s.y;
        }
        const size_t idx = ((size_t)(b_*SS + q0 + r))*DM + h*DKK + c2;
        ushort2 hv, lv;
        hv.x = f2bf(o0); lv.x = f2bf(o0 - bf2f(hv.x));
        hv.y = f2bf(o1); lv.y = f2bf(o1 - bf2f(hv.y));
        *(ushort2*)&AoH[idx] = hv;
        *(ushort2*)&AoL[idx] = lv;
    }
}

// ============================================================
extern "C" void kernel_launch(void* const* d_in, const int* in_sizes, int n_in,
                              void* d_out, int out_size, void* d_ws, size_t ws_size,
                              hipStream_t stream)
{
    (void)in_sizes; (void)n_in; (void)out_size; (void)ws_size;

    const float* q   = (const float*)d_in[0];
    const float* k   = (const float*)d_in[1];
    const float* v   = (const float*)d_in[2];
    const float* Wq  = (const float*)d_in[3];
    const float* bq  = (const float*)d_in[4];
    const float* Wk  = (const float*)d_in[5];
    const float* bk  = (const float*)d_in[6];
    const float* Wv  = (const float*)d_in[7];
    const float* bv  = (const float*)d_in[8];
    const float* Wo  = (const float*)d_in[9];
    const float* bo  = (const float*)d_in[10];
    const float* gam = (const float*)d_in[11];
    float* out = (float*)d_out;

    const size_t NE = (size_t)NTOK * DM;            // 4,194,304 elems
    float* Qh = (float*)d_ws;                       // fp32 16.8MB
    float* Kt = Qh + NE;                            // fp32 [B,H,DK,S]
    float* Vh = Kt + NE;                            // fp32
    u16* qh = (u16*)(Vh + NE);                      // 6 x bf16 x-splits, 8.4MB each
    u16* ql = qh + NE;
    u16* kh = ql + NE;
    u16* kl = kh + NE;
    u16* vh = kl + NE;
    u16* vl = vh + NE;
    u16* wb = vl + NE;                              // 8 x bf16 W-splits, 2.1MB each
    // total ~117.4MB of d_ws

    split_x3<<<12288, 256, 0, stream>>>(q, k, v, qh, ql, kh, kl, vh, vl);
    split_w4<<<4096,  256, 0, stream>>>(Wq, Wk, Wv, Wo, wb);

    gemm_qkv<<<1536, 256, 0, stream>>>(qh, ql, kh, kl, vh, vl, wb,
                                       bq, bk, bv, Qh, Kt, Vh);

    // attn reuses qh/ql as the concat hi/lo output
    attn_kernel<<<4096, 512, 0, stream>>>(Qh, Kt, Vh, gam, qh, ql);

    gemm_out<<<512, 256, 0, stream>>>(qh, ql, wb, bo, out);
}

// Round 9
// 745.264 us; speedup vs baseline: 2.2715x; 1.0128x over previous
//
#include <hip/hip_runtime.h>
#include <math.h>

#define BB 4
#define SS 1024
#define DM 1024
#define HH 16
#define DKK 64
#define NTOK (BB*SS)   // 4096
#define QT 16          // q-rows per attn block

typedef __attribute__((ext_vector_type(8))) short bf16x8;
typedef __attribute__((ext_vector_type(4))) float f32x4;
typedef unsigned short u16;

// bf16 round-to-nearest-even, manual
__device__ __forceinline__ u16 f2bf(float x) {
    unsigned int u = __float_as_uint(x);
    u += 0x7fffu + ((u >> 16) & 1u);
    return (u16)(u >> 16);
}
__device__ __forceinline__ float bf2f(u16 b) {
    return __uint_as_float((unsigned int)b << 16);
}

__device__ __forceinline__ void split4(const float4 v, ushort4* hv, ushort4* lv) {
    hv->x = f2bf(v.x); lv->x = f2bf(v.x - bf2f(hv->x));
    hv->y = f2bf(v.y); lv->y = f2bf(v.y - bf2f(hv->y));
    hv->z = f2bf(v.z); lv->z = f2bf(v.z - bf2f(hv->z));
    hv->w = f2bf(v.w); lv->w = f2bf(v.w - bf2f(hv->w));
}

// ============================================================
// split q,k,v (3 x 4M elems) in one launch: 12288 blocks.
// ============================================================
__global__ __launch_bounds__(256) void split_x3(
    const float* __restrict__ a, const float* __restrict__ b, const float* __restrict__ c,
    u16* __restrict__ ah, u16* __restrict__ al,
    u16* __restrict__ bh, u16* __restrict__ bl,
    u16* __restrict__ ch, u16* __restrict__ cl)
{
    const int t = blockIdx.x >> 12;                       // 4096 blocks/tensor
    const int i = ((blockIdx.x & 4095) << 8) + threadIdx.x;  // float4 idx < 1048576
    const float* in = (t == 0) ? a : (t == 1) ? b : c;
    u16* oh = (t == 0) ? ah : (t == 1) ? bh : ch;
    u16* ol = (t == 0) ? al : (t == 1) ? bl : cl;
    const float4 v = *(const float4*)&in[(size_t)i * 4];
    ushort4 hv, lv;
    split4(v, &hv, &lv);
    *(ushort4*)&oh[(size_t)i * 4] = hv;
    *(ushort4*)&ol[(size_t)i * 4] = lv;
}

// ============================================================
// split Wq,Wk,Wv,Wo (4 x 1M elems) in one launch: 4096 blocks.
// Outputs consecutive: {qh,ql,kh,kl,vh,vl,oh,ol}, each 1M u16.
// ============================================================
__global__ __launch_bounds__(256) void split_w4(
    const float* __restrict__ wq, const float* __restrict__ wk,
    const float* __restrict__ wv, const float* __restrict__ wo,
    u16* __restrict__ base)
{
    const int t = blockIdx.x >> 10;                       // 1024 blocks/tensor
    const int i = ((blockIdx.x & 1023) << 8) + threadIdx.x;  // float4 idx < 262144
    const float* in = (t == 0) ? wq : (t == 1) ? wk : (t == 2) ? wv : wo;
    u16* oh = base + (size_t)(2 * t)     * 1048576;
    u16* ol = base + (size_t)(2 * t + 1) * 1048576;
    const float4 v = *(const float4*)&in[(size_t)i * 4];
    ushort4 hv, lv;
    split4(v, &hv, &lv);
    *(ushort4*)&oh[(size_t)i * 4] = hv;
    *(ushort4*)&ol[(size_t)i * 4] = lv;
}

// ============================================================
// MFMA GEMM core (3-product bf16 split) with 2-deep REGISTER
// double-buffer: loads for K-step t+1 are in flight while
// MFMAs crunch step t (fixes R7's latency-bound serial loop).
// tile 128x64, 4 waves (2x2), wave 64x32 = 4x2 frags 16x16x32.
// ============================================================
#define LOADF(bah, bal, bbh, bbl, KT) do {                                      \
    _Pragma("unroll") for (int i_ = 0; i_ < 4; ++i_) {                          \
        bah[i_] = *(const bf16x8*)&Xh[arow + (size_t)i_*16*1024 + (KT)];        \
        bal[i_] = *(const bf16x8*)&Xl[arow + (size_t)i_*16*1024 + (KT)];        \
    }                                                                           \
    _Pragma("unroll") for (int j_ = 0; j_ < 2; ++j_) {                          \
        bbh[j_] = *(const bf16x8*)&Wh[brow + (size_t)j_*16*1024 + (KT)];        \
        bbl[j_] = *(const bf16x8*)&Wl[brow + (size_t)j_*16*1024 + (KT)];        \
    }                                                                           \
} while (0)

#define MFMAS(bah, bal, bbh, bbl) do {                                          \
    _Pragma("unroll") for (int i_ = 0; i_ < 4; ++i_)                            \
    _Pragma("unroll") for (int j_ = 0; j_ < 2; ++j_) {                          \
        acc[i_][j_] = __builtin_amdgcn_mfma_f32_16x16x32_bf16(bah[i_], bbh[j_], acc[i_][j_], 0, 0, 0); \
        acc[i_][j_] = __builtin_amdgcn_mfma_f32_16x16x32_bf16(bah[i_], bbl[j_], acc[i_][j_], 0, 0, 0); \
        acc[i_][j_] = __builtin_amdgcn_mfma_f32_16x16x32_bf16(bal[i_], bbh[j_], acc[i_][j_], 0, 0, 0); \
    }                                                                           \
} while (0)

__device__ __forceinline__ void gemm_core(
    const u16* __restrict__ Xh, const u16* __restrict__ Xl,
    const u16* __restrict__ Wh, const u16* __restrict__ Wl,
    const float* __restrict__ bias, float* __restrict__ Y,
    int lin, int mode /*0 flat, 1 head-split, 2 head-split-T*/)
{
    const int tid  = threadIdx.x;
    const int lane = tid & 63;
    const int w    = tid >> 6;
    const int wr   = w >> 1, wc = w & 1;
    const int r16  = lane & 15, kg = lane >> 4;

    // XCD swizzle over 512 blocks
    const int swz = (lin & 7) * 64 + (lin >> 3);
    const int mt  = swz >> 4, nt = swz & 15;

    const int mbase = mt * 128 + wr * 64;
    const int obase = nt * 64  + wc * 32;

    const size_t arow = (size_t)(mbase + r16) * 1024 + kg * 8;
    const size_t brow = (size_t)(obase + r16) * 1024 + kg * 8;

    f32x4 acc[4][2];
    const f32x4 zero = {0.f, 0.f, 0.f, 0.f};
    #pragma unroll
    for (int i = 0; i < 4; ++i)
        #pragma unroll
        for (int j = 0; j < 2; ++j) acc[i][j] = zero;

    bf16x8 ah0[4], al0[4], bh0[2], bl0[2];
    bf16x8 ah1[4], al1[4], bh1[2], bl1[2];

    LOADF(ah0, al0, bh0, bl0, 0);
    #pragma unroll 1
    for (int kt = 0; kt < 1024; kt += 64) {
        LOADF(ah1, al1, bh1, bl1, kt + 32);   // next step in flight
        MFMAS(ah0, al0, bh0, bl0);
        if (kt + 64 < 1024)
            LOADF(ah0, al0, bh0, bl0, kt + 64);
        MFMAS(ah1, al1, bh1, bl1);
    }

    #pragma unroll
    for (int i = 0; i < 4; ++i) {
        const int mrow0 = mbase + i * 16 + kg * 4;   // 4 consecutive m rows
        #pragma unroll
        for (int j = 0; j < 2; ++j) {
            const int col = obase + j * 16 + r16;
            const float bv = bias[col];
            if (mode == 2) {
                const int b_ = mrow0 >> 10, s_ = mrow0 & 1023;
                const int h_ = col >> 6, d_ = col & 63;
                float4 o;
                o.x = acc[i][j][0] + bv; o.y = acc[i][j][1] + bv;
                o.z = acc[i][j][2] + bv; o.w = acc[i][j][3] + bv;
                *(float4*)&Y[(((size_t)(b_ * HH + h_)) * DKK + d_) * SS + s_] = o;
            } else if (mode == 1) {
                #pragma unroll
                for (int rg = 0; rg < 4; ++rg) {
                    const int m = mrow0 + rg;
                    const int b_ = m >> 10, s_ = m & 1023;
                    const int h_ = col >> 6, d_ = col & 63;
                    Y[(((size_t)(b_ * HH + h_)) * SS + s_) * DKK + d_] = acc[i][j][rg] + bv;
                }
            } else {
                #pragma unroll
                for (int rg = 0; rg < 4; ++rg)
                    Y[(size_t)(mrow0 + rg) * 1024 + col] = acc[i][j][rg] + bv;
            }
        }
    }
}

// Batched Q/K/V projection: 1536 blocks (3 x 512).
__global__ __launch_bounds__(256) void gemm_qkv(
    const u16* __restrict__ qh, const u16* __restrict__ ql,
    const u16* __restrict__ kh, const u16* __restrict__ kl,
    const u16* __restrict__ vh, const u16* __restrict__ vl,
    const u16* __restrict__ wbase,
    const float* __restrict__ bq, const float* __restrict__ bk, const float* __restrict__ bv,
    float* __restrict__ Qh, float* __restrict__ Kt, float* __restrict__ Vh)
{
    const int z   = blockIdx.x >> 9;     // 0,1,2
    const int lin = blockIdx.x & 511;
    const u16 *Xh, *Xl, *Wh, *Wl; const float* bias; float* Y; int mode;
    if (z == 0)      { Xh=qh; Xl=ql; Wh=wbase;           Wl=wbase+1048576;   bias=bq; Y=Qh; mode=1; }
    else if (z == 1) { Xh=kh; Xl=kl; Wh=wbase+2*1048576; Wl=wbase+3*1048576; bias=bk; Y=Kt; mode=2; }
    else             { Xh=vh; Xl=vl; Wh=wbase+4*1048576; Wl=wbase+5*1048576; bias=bv; Y=Vh; mode=1; }
    gemm_core(Xh, Xl, Wh, Wl, bias, Y, lin, mode);
}

// Output projection (flat out), 512 blocks.
__global__ __launch_bounds__(256) void gemm_out(
    const u16* __restrict__ Xh, const u16* __restrict__ Xl,
    const u16* __restrict__ wbase, const float* __restrict__ bias,
    float* __restrict__ Y)
{
    gemm_core(Xh, Xl, wbase + 6*1048576, wbase + 7*1048576, bias, Y, blockIdx.x, 0);
}

// ============================================================
// Fused attention (R5/R6-verified). Epilogue writes hi/lo
// bf16 split of concat.
// ============================================================
__global__ __launch_bounds__(512) void attn_kernel(
    const float* __restrict__ Qh, const float* __restrict__ Kt,
    const float* __restrict__ Vh, const float* __restrict__ gammas,
    u16* __restrict__ AoH, u16* __restrict__ AoL)
{
    __shared__ float sS[QT][1024];   // 64 KB score rows
    __shared__ float sQ[QT][64];     // 4 KB

    const int tid  = threadIdx.x;
    const int lane = tid & 63;
    const int w    = tid >> 6;       // 0..7

    const int bid = ((blockIdx.x & 7) << 9) | (blockIdx.x >> 3);
    const int bh  = bid >> 6;
    const int qt  = bid & 63;
    const int q0  = qt * QT;
    const int h   = bh & (HH - 1);
    const int b_  = bh >> 4;

    const float* Qb  = Qh + (size_t)bh * SS * DKK;
    const float* Ktb = Kt + (size_t)bh * DKK * SS;   // [64][1024]
    const float* Vb  = Vh + (size_t)bh * SS * DKK;

    const float g = gammas[h];
    const float gamma = -(fmaxf(g, 0.f) + log1pf(__expf(-fabsf(g))));

    {   // load Q tile: 512 thr x float2
        const int r = tid >> 5, c2 = (tid & 31) << 1;
        *(float2*)&sQ[r][c2] = *(const float2*)&Qb[(size_t)(q0 + r)*DKK + c2];
    }
    __syncthreads();

    // ---------- phase 1: QK^T; wave w owns k1=w*64+lane, k2=k1+512 ----------
    {
        const int k1 = w*64 + lane;           // coalesced across lanes
        float acc1[QT], acc2[QT];
        #pragma unroll
        for (int r = 0; r < QT; ++r) { acc1[r] = 0.f; acc2[r] = 0.f; }

        #pragma unroll
        for (int d0 = 0; d0 < 64; d0 += 4) {
            const float* col = &Ktb[(size_t)d0 * SS + k1];
            const float a0 = col[0*SS], a1 = col[1*SS], a2 = col[2*SS], a3 = col[3*SS];
            const float b0 = col[0*SS+512], b1 = col[1*SS+512],
                        b2 = col[2*SS+512], b3 = col[3*SS+512];
            #pragma unroll
            for (int r = 0; r < QT; ++r) {
                const float4 q4 = *(const float4*)&sQ[r][d0];   // bcast, free
                float t1 = acc1[r], t2 = acc2[r];
                t1 = fmaf(a0, q4.x, t1); t2 = fmaf(b0, q4.x, t2);
                t1 = fmaf(a1, q4.y, t1); t2 = fmaf(b1, q4.y, t2);
                t1 = fmaf(a2, q4.z, t1); t2 = fmaf(b2, q4.z, t2);
                t1 = fmaf(a3, q4.w, t1); t2 = fmaf(b3, q4.w, t2);
                acc1[r] = t1; acc2[r] = t2;
            }
        }
        #pragma unroll
        for (int r = 0; r < QT; ++r) {
            sS[r][k1]       = acc1[r] * 0.125f;   // 1/sqrt(64)
            sS[r][k1 + 512] = acc2[r] * 0.125f;
        }
    }
    __syncthreads();

    // ---------- phase 2: wave w owns rows 2w, 2w+1 ----------
    #pragma unroll 1
    for (int rr = 0; rr < 2; ++rr) {
        const int r = w*2 + rr;
        const int q = q0 + r;

        float sv[16], ex[16];
        #pragma unroll
        for (int seg = 0; seg < 4; ++seg) {
            const float4 t = *(const float4*)&sS[r][seg*256 + lane*4];  // conflict-free
            sv[seg*4+0] = t.x; sv[seg*4+1] = t.y; sv[seg*4+2] = t.z; sv[seg*4+3] = t.w;
        }
        float m1 = -INFINITY;
        #pragma unroll
        for (int t = 0; t < 16; ++t) m1 = fmaxf(m1, sv[t]);
        #pragma unroll
        for (int off = 32; off; off >>= 1) m1 = fmaxf(m1, __shfl_xor(m1, off, 64));
        float s1 = 0.f;
        #pragma unroll
        for (int t = 0; t < 16; ++t) { ex[t] = __expf(sv[t] - m1); s1 += ex[t]; }
        #pragma unroll
        for (int off = 32; off; off >>= 1) s1 += __shfl_xor(s1, off, 64);
        const float inv_s1 = 1.f / s1;

        float pref[16], sc[4];
        #pragma unroll
        for (int seg = 0; seg < 4; ++seg) {
            float run = 0.f;
            #pragma unroll
            for (int j = 0; j < 4; ++j) {
                const int k = seg*256 + lane*4 + j;
                const float p = (k <= q) ? ex[seg*4+j] * inv_s1 : 0.f;
                run += p;
                pref[seg*4+j] = run;
            }
            sc[seg] = run;
        }
        const float ls0 = sc[0], ls1 = sc[1], ls2 = sc[2], ls3 = sc[3];
        #pragma unroll
        for (int off = 1; off < 64; off <<= 1) {
            const float t0 = __shfl_up(sc[0], off, 64);
            const float t1 = __shfl_up(sc[1], off, 64);
            const float t2 = __shfl_up(sc[2], off, 64);
            const float t3 = __shfl_up(sc[3], off, 64);
            if (lane >= off) { sc[0] += t0; sc[1] += t1; sc[2] += t2; sc[3] += t3; }
        }
        const float st0 = __shfl(sc[0], 63, 64);
        const float st1 = __shfl(sc[1], 63, 64);
        const float st2 = __shfl(sc[2], 63, 64);
        const float st3 = __shfl(sc[3], 63, 64);
        const float carry[4] = {0.f, st0, st0+st1, st0+st1+st2};
        const float excl[4]  = {sc[0]-ls0, sc[1]-ls1, sc[2]-ls2, sc[3]-ls3};
        const float total = st0 + st1 + st2 + st3;

        #pragma unroll
        for (int seg = 0; seg < 4; ++seg) {
            #pragma unroll
            for (int j = 0; j < 4; ++j) {
                const int k = seg*256 + lane*4 + j;
                const int t = seg*4 + j;
                if (k <= q) {
                    const float distcum = carry[seg] + excl[seg] + pref[t];
                    const float dsc = sqrtf(fmaxf((total - distcum) * (float)(q - k), 0.f));
                    const float te  = fminf(fmaxf(__expf(dsc * gamma), 1e-5f), 1e5f);
                    sv[t] = sv[t] * te;
                } else {
                    sv[t] = -INFINITY;
                }
            }
        }

        float m2 = -INFINITY;
        #pragma unroll
        for (int t = 0; t < 16; ++t) m2 = fmaxf(m2, sv[t]);
        #pragma unroll
        for (int off = 32; off; off >>= 1) m2 = fmaxf(m2, __shfl_xor(m2, off, 64));
        float s2 = 0.f;
        #pragma unroll
        for (int t = 0; t < 16; ++t) { ex[t] = __expf(sv[t] - m2); s2 += ex[t]; }
        #pragma unroll
        for (int off = 32; off; off >>= 1) s2 += __shfl_xor(s2, off, 64);
        const float inv2 = 1.f / s2;

        #pragma unroll
        for (int seg = 0; seg < 4; ++seg) {
            float4 o;
            o.x = ex[seg*4+0]*inv2; o.y = ex[seg*4+1]*inv2;
            o.z = ex[seg*4+2]*inv2; o.w = ex[seg*4+3]*inv2;
            *(float4*)&sS[r][seg*256 + lane*4] = o;
        }
    }
    __syncthreads();

    // ---------- phase 3: PV, k split 8-way across waves ----------
    const int kmax = q0 + QT;
    float pacc[16];
    #pragma unroll
    for (int r = 0; r < 16; ++r) pacc[r] = 0.f;

    #pragma unroll 1
    for (int k4 = w*4; k4 < kmax; k4 += 32) {
        const float va = Vb[(size_t)(k4+0)*DKK + lane];
        const float vb = Vb[(size_t)(k4+1)*DKK + lane];
        const float vc = Vb[(size_t)(k4+2)*DKK + lane];
        const float vd = Vb[(size_t)(k4+3)*DKK + lane];
        #pragma unroll
        for (int r = 0; r < 16; ++r) {
            const float4 p4 = *(const float4*)&sS[r][k4];
            pacc[r] = fmaf(p4.x, va, pacc[r]);
            pacc[r] = fmaf(p4.y, vb, pacc[r]);
            pacc[r] = fmaf(p4.z, vc, pacc[r]);
            pacc[r] = fmaf(p4.w, vd, pacc[r]);
        }
    }
    __syncthreads();

    float* scr = &sS[0][0];
    #pragma unroll
    for (int r = 0; r < 16; ++r)
        scr[(w*16 + r)*64 + lane] = pacc[r];
    __syncthreads();

    {   // reduce 8 wave-partials; write hi/lo bf16 split, concat layout
        const int r = tid >> 5, c2 = (tid & 31) << 1;
        float o0 = 0.f, o1 = 0.f;
        #pragma unroll
        for (int p = 0; p < 8; ++p) {
            const float2 s = *(const float2*)&scr[(p*16 + r)*64 + c2];
            o0 += s.x; o1 += s.y;
        }
        const size_t idx = ((size_t)(b_*SS + q0 + r))*DM + h*DKK + c2;
        ushort2 hv, lv;
        hv.x = f2bf(o0); lv.x = f2bf(o0 - bf2f(hv.x));
        hv.y = f2bf(o1); lv.y = f2bf(o1 - bf2f(hv.y));
        *(ushort2*)&AoH[idx] = hv;
        *(ushort2*)&AoL[idx] = lv;
    }
}

// ============================================================
extern "C" void kernel_launch(void* const* d_in, const int* in_sizes, int n_in,
                              void* d_out, int out_size, void* d_ws, size_t ws_size,
                              hipStream_t stream)
{
    (void)in_sizes; (void)n_in; (void)out_size; (void)ws_size;

    const float* q   = (const float*)d_in[0];
    const float* k   = (const float*)d_in[1];
    const float* v   = (const float*)d_in[2];
    const float* Wq  = (const float*)d_in[3];
    const float* bq  = (const float*)d_in[4];
    const float* Wk  = (const float*)d_in[5];
    const float* bk  = (const float*)d_in[6];
    const float* Wv  = (const float*)d_in[7];
    const float* bv  = (const float*)d_in[8];
    const float* Wo  = (const float*)d_in[9];
    const float* bo  = (const float*)d_in[10];
    const float* gam = (const float*)d_in[11];
    float* out = (float*)d_out;

    const size_t NE = (size_t)NTOK * DM;            // 4,194,304 elems
    float* Qh = (float*)d_ws;                       // fp32 16.8MB
    float* Kt = Qh + NE;                            // fp32 [B,H,DK,S]
    float* Vh = Kt + NE;                            // fp32
    u16* qh = (u16*)(Vh + NE);                      // 6 x bf16 x-splits
    u16* ql = qh + NE;
    u16* kh = ql + NE;
    u16* kl = kh + NE;
    u16* vh = kl + NE;
    u16* vl = vh + NE;
    u16* wb = vl + NE;                              // 8 x bf16 W-splits

    split_x3<<<12288, 256, 0, stream>>>(q, k, v, qh, ql, kh, kl, vh, vl);
    split_w4<<<4096,  256, 0, stream>>>(Wq, Wk, Wv, Wo, wb);

    gemm_qkv<<<1536, 256, 0, stream>>>(qh, ql, kh, kl, vh, vl, wb,
                                       bq, bk, bv, Qh, Kt, Vh);

    // attn reuses qh/ql as the concat hi/lo output
    attn_kernel<<<4096, 512, 0, stream>>>(Qh, Kt, Vh, gam, qh, ql);

    gemm_out<<<512, 256, 0, stream>>>(qh, ql, wb, bo, out);
}

// Round 12
// 562.385 us; speedup vs baseline: 3.0102x; 1.3252x over previous
//
#include <hip/hip_runtime.h>
#include <math.h>

#define BB 4
#define SS 1024
#define DM 1024
#define HH 16
#define DKK 64
#define NTOK (BB*SS)   // 4096
#define QT 16          // q-rows per attn block

typedef __attribute__((ext_vector_type(8))) short bf16x8;
typedef __attribute__((ext_vector_type(4))) float f32x4;
typedef unsigned short u16;

// bf16 round-to-nearest-even, manual
__device__ __forceinline__ u16 f2bf(float x) {
    unsigned int u = __float_as_uint(x);
    u += 0x7fffu + ((u >> 16) & 1u);
    return (u16)(u >> 16);
}
__device__ __forceinline__ float bf2f(u16 b) {
    return __uint_as_float((unsigned int)b << 16);
}

__device__ __forceinline__ void split4(const float4 v, ushort4* hv, ushort4* lv) {
    hv->x = f2bf(v.x); lv->x = f2bf(v.x - bf2f(hv->x));
    hv->y = f2bf(v.y); lv->y = f2bf(v.y - bf2f(hv->y));
    hv->z = f2bf(v.z); lv->z = f2bf(v.z - bf2f(hv->z));
    hv->w = f2bf(v.w); lv->w = f2bf(v.w - bf2f(hv->w));
}

// ============================================================
// split q,k,v (3 x 4M elems) in one launch: 12288 blocks.
// ============================================================
__global__ __launch_bounds__(256) void split_x3(
    const float* __restrict__ a, const float* __restrict__ b, const float* __restrict__ c,
    u16* __restrict__ ah, u16* __restrict__ al,
    u16* __restrict__ bh, u16* __restrict__ bl,
    u16* __restrict__ ch, u16* __restrict__ cl)
{
    const int t = blockIdx.x >> 12;                       // 4096 blocks/tensor
    const int i = ((blockIdx.x & 4095) << 8) + threadIdx.x;  // float4 idx < 1048576
    const float* in = (t == 0) ? a : (t == 1) ? b : c;
    u16* oh = (t == 0) ? ah : (t == 1) ? bh : ch;
    u16* ol = (t == 0) ? al : (t == 1) ? bl : cl;
    const float4 v = *(const float4*)&in[(size_t)i * 4];
    ushort4 hv, lv;
    split4(v, &hv, &lv);
    *(ushort4*)&oh[(size_t)i * 4] = hv;
    *(ushort4*)&ol[(size_t)i * 4] = lv;
}

// ============================================================
// split Wq,Wk,Wv,Wo (4 x 1M elems) in one launch: 4096 blocks.
// Outputs consecutive: {qh,ql,kh,kl,vh,vl,oh,ol}, each 1M u16.
// ============================================================
__global__ __launch_bounds__(256) void split_w4(
    const float* __restrict__ wq, const float* __restrict__ wk,
    const float* __restrict__ wv, const float* __restrict__ wo,
    u16* __restrict__ base)
{
    const int t = blockIdx.x >> 10;                       // 1024 blocks/tensor
    const int i = ((blockIdx.x & 1023) << 8) + threadIdx.x;  // float4 idx < 262144
    const float* in = (t == 0) ? wq : (t == 1) ? wk : (t == 2) ? wv : wo;
    u16* oh = base + (size_t)(2 * t)     * 1048576;
    u16* ol = base + (size_t)(2 * t + 1) * 1048576;
    const float4 v = *(const float4*)&in[(size_t)i * 4];
    ushort4 hv, lv;
    split4(v, &hv, &lv);
    *(ushort4*)&oh[(size_t)i * 4] = hv;
    *(ushort4*)&ol[(size_t)i * 4] = lv;
}

// ============================================================
// m97-class LDS-staged MFMA GEMM, 3-product bf16 split.
// Tile 128xBN, BK=32, 256 thr = 4 waves (2x2), LDS dbuf.
// Loop: {issue global loads(t+1) -> ds_read+48 MFMA on t ->
// barrier -> ds_write(t+1) -> barrier}  (T14 issue-early /
// write-late: HBM/L2 latency hides under the MFMA block).
// Fragment formulas identical to the R6-verified direct-global
// kernel; only the byte path changed (global->reg->LDS->frag).
// ============================================================
template<int BN>
__device__ __forceinline__ void gemm_lds_core(
    const u16* __restrict__ Xh, const u16* __restrict__ Xl,
    const u16* __restrict__ Wh, const u16* __restrict__ Wl,
    const float* __restrict__ bias, float* __restrict__ Y,
    int lin, int mode /*0 flat, 1 head-split, 2 head-split-T*/)
{
    constexpr int NJ   = BN / 32;     // B frags per wave (128->4, 64->2)
    constexpr int NT_N = 1024 / BN;   // n tiles (8 or 16)
    constexpr int NWG  = 32 * NT_N;   // blocks per gemm (256 or 512)

    __shared__ u16 sXh[2][128 * 32];
    __shared__ u16 sXl[2][128 * 32];
    __shared__ u16 sWh[2][BN * 32];
    __shared__ u16 sWl[2][BN * 32];

    const int tid  = threadIdx.x;
    const int lane = tid & 63;
    const int w    = tid >> 6;
    const int wr   = w >> 1, wc = w & 1;
    const int r16  = lane & 15, kg = lane >> 4;

    // XCD-bijective swizzle (NWG divisible by 8)
    const int swz = (lin & 7) * (NWG >> 3) + (lin >> 3);
    const int mt  = swz / NT_N, nt = swz % NT_N;
    const int m0  = mt * 128,  n0 = nt * BN;

    // staging mapping: flat 16B-chunk f = p*256 + tid; row = f>>2, k16 = f&3
    const int srow = tid >> 2;
    const int sk   = (tid & 3) * 8;

    const u16* gXh = Xh + (size_t)(m0 + srow) * 1024 + sk;
    const u16* gXl = Xl + (size_t)(m0 + srow) * 1024 + sk;
    const u16* gWh = Wh + (size_t)(n0 + srow) * 1024 + sk;
    const u16* gWl = Wl + (size_t)(n0 + srow) * 1024 + sk;

    bf16x8 rxh0, rxh1, rxl0, rxl1, rwh0, rwh1, rwl0, rwl1;

    auto LDG = [&](int kt) {
        rxh0 = *(const bf16x8*)&gXh[kt];
        rxh1 = *(const bf16x8*)&gXh[kt + 64 * 1024];
        rxl0 = *(const bf16x8*)&gXl[kt];
        rxl1 = *(const bf16x8*)&gXl[kt + 64 * 1024];
        rwh0 = *(const bf16x8*)&gWh[kt];
        rwl0 = *(const bf16x8*)&gWl[kt];
        if constexpr (BN == 128) {
            rwh1 = *(const bf16x8*)&gWh[kt + 64 * 1024];
            rwl1 = *(const bf16x8*)&gWl[kt + 64 * 1024];
        }
    };
    auto STORE = [&](int b) {
        const int o = tid * 8;           // element offset = f*8
        *(bf16x8*)&sXh[b][o]        = rxh0;
        *(bf16x8*)&sXh[b][o + 2048] = rxh1;
        *(bf16x8*)&sXl[b][o]        = rxl0;
        *(bf16x8*)&sXl[b][o + 2048] = rxl1;
        *(bf16x8*)&sWh[b][o]        = rwh0;
        *(bf16x8*)&sWl[b][o]        = rwl0;
        if constexpr (BN == 128) {
            *(bf16x8*)&sWh[b][o + 2048] = rwh1;
            *(bf16x8*)&sWl[b][o + 2048] = rwl1;
        }
    };

    f32x4 acc[4][NJ];
    #pragma unroll
    for (int i = 0; i < 4; ++i)
        #pragma unroll
        for (int j = 0; j < NJ; ++j)
            acc[i][j] = (f32x4){0.f, 0.f, 0.f, 0.f};

    auto COMPUTE = [&](int b) {
        bf16x8 fah[4], fal[4];
        #pragma unroll
        for (int i = 0; i < 4; ++i) {
            const int ro = (wr * 64 + i * 16 + r16) * 32 + kg * 8;
            fah[i] = *(const bf16x8*)&sXh[b][ro];
            fal[i] = *(const bf16x8*)&sXl[b][ro];
        }
        #pragma unroll
        for (int j = 0; j < NJ; ++j) {
            const int ro = (wc * (BN / 2) + j * 16 + r16) * 32 + kg * 8;
            const bf16x8 fbh = *(const bf16x8*)&sWh[b][ro];
            const bf16x8 fbl = *(const bf16x8*)&sWl[b][ro];
            #pragma unroll
            for (int i = 0; i < 4; ++i) {
                acc[i][j] = __builtin_amdgcn_mfma_f32_16x16x32_bf16(fah[i], fbh, acc[i][j], 0, 0, 0);
                acc[i][j] = __builtin_amdgcn_mfma_f32_16x16x32_bf16(fah[i], fbl, acc[i][j], 0, 0, 0);
                acc[i][j] = __builtin_amdgcn_mfma_f32_16x16x32_bf16(fal[i], fbh, acc[i][j], 0, 0, 0);
            }
        }
    };

    LDG(0);
    STORE(0);
    __syncthreads();
    int b = 0;
    #pragma unroll 1
    for (int kt = 0; kt < 1024; kt += 32) {
        const bool more = (kt + 32 < 1024);
        if (more) LDG(kt + 32);     // in flight across the MFMA block
        COMPUTE(b);
        __syncthreads();            // all reads of lds[b] done
        if (more) {
            STORE(b ^ 1);           // vmcnt waits here, latency already hidden
            __syncthreads();        // staged tile visible
        }
        b ^= 1;
    }

    const int mbase = m0 + wr * 64;
    const int obase = n0 + wc * (BN / 2);
    #pragma unroll
    for (int i = 0; i < 4; ++i) {
        const int mrow0 = mbase + i * 16 + kg * 4;   // 4 consecutive m rows
        #pragma unroll
        for (int j = 0; j < NJ; ++j) {
            const int col = obase + j * 16 + r16;
            const float bv = bias[col];
            if (mode == 2) {
                const int b_ = mrow0 >> 10, s_ = mrow0 & 1023;
                const int h_ = col >> 6, d_ = col & 63;
                float4 o;
                o.x = acc[i][j][0] + bv; o.y = acc[i][j][1] + bv;
                o.z = acc[i][j][2] + bv; o.w = acc[i][j][3] + bv;
                *(float4*)&Y[(((size_t)(b_ * HH + h_)) * DKK + d_) * SS + s_] = o;
            } else if (mode == 1) {
                #pragma unroll
                for (int rg = 0; rg < 4; ++rg) {
                    const int m = mrow0 + rg;
                    const int b_ = m >> 10, s_ = m & 1023;
                    const int h_ = col >> 6, d_ = col & 63;
                    Y[(((size_t)(b_ * HH + h_)) * SS + s_) * DKK + d_] = acc[i][j][rg] + bv;
                }
            } else {
                #pragma unroll
                for (int rg = 0; rg < 4; ++rg)
                    Y[(size_t)(mrow0 + rg) * 1024 + col] = acc[i][j][rg] + bv;
            }
        }
    }
}

// Batched Q/K/V projection: 768 blocks (3 x 256), BN=128.
__global__ __launch_bounds__(256) void gemm_qkv(
    const u16* __restrict__ qh, const u16* __restrict__ ql,
    const u16* __restrict__ kh, const u16* __restrict__ kl,
    const u16* __restrict__ vh, const u16* __restrict__ vl,
    const u16* __restrict__ wbase,
    const float* __restrict__ bq, const float* __restrict__ bk, const float* __restrict__ bv,
    float* __restrict__ Qh, float* __restrict__ Kt, float* __restrict__ Vh)
{
    const int z   = blockIdx.x >> 8;     // 0,1,2
    const int lin = blockIdx.x & 255;
    const u16 *Xh, *Xl, *Wh, *Wl; const float* bias; float* Y; int mode;
    if (z == 0)      { Xh=qh; Xl=ql; Wh=wbase;           Wl=wbase+1048576;   bias=bq; Y=Qh; mode=1; }
    else if (z == 1) { Xh=kh; Xl=kl; Wh=wbase+2*1048576; Wl=wbase+3*1048576; bias=bk; Y=Kt; mode=2; }
    else             { Xh=vh; Xl=vl; Wh=wbase+4*1048576; Wl=wbase+5*1048576; bias=bv; Y=Vh; mode=1; }
    gemm_lds_core<128>(Xh, Xl, Wh, Wl, bias, Y, lin, mode);
}

// Output projection (flat out), 512 blocks, BN=64.
__global__ __launch_bounds__(256) void gemm_out(
    const u16* __restrict__ Xh, const u16* __restrict__ Xl,
    const u16* __restrict__ wbase, const float* __restrict__ bias,
    float* __restrict__ Y)
{
    gemm_lds_core<64>(Xh, Xl, wbase + 6*1048576, wbase + 7*1048576, bias, Y, blockIdx.x, 0);
}

// ============================================================
// Fused attention (R5-R9 verified, byte-identical to R9).
// Epilogue writes hi/lo bf16 split of concat.
// ============================================================
__global__ __launch_bounds__(512) void attn_kernel(
    const float* __restrict__ Qh, const float* __restrict__ Kt,
    const float* __restrict__ Vh, const float* __restrict__ gammas,
    u16* __restrict__ AoH, u16* __restrict__ AoL)
{
    __shared__ float sS[QT][1024];   // 64 KB score rows
    __shared__ float sQ[QT][64];     // 4 KB

    const int tid  = threadIdx.x;
    const int lane = tid & 63;
    const int w    = tid >> 6;       // 0..7

    const int bid = ((blockIdx.x & 7) << 9) | (blockIdx.x >> 3);
    const int bh  = bid >> 6;
    const int qt  = bid & 63;
    const int q0  = qt * QT;
    const int h   = bh & (HH - 1);
    const int b_  = bh >> 4;

    const float* Qb  = Qh + (size_t)bh * SS * DKK;
    const float* Ktb = Kt + (size_t)bh * DKK * SS;   // [64][1024]
    const float* Vb  = Vh + (size_t)bh * SS * DKK;

    const float g = gammas[h];
    const float gamma = -(fmaxf(g, 0.f) + log1pf(__expf(-fabsf(g))));

    {   // load Q tile: 512 thr x float2
        const int r = tid >> 5, c2 = (tid & 31) << 1;
        *(float2*)&sQ[r][c2] = *(const float2*)&Qb[(size_t)(q0 + r)*DKK + c2];
    }
    __syncthreads();

    // ---------- phase 1: QK^T; wave w owns k1=w*64+lane, k2=k1+512 ----------
    {
        const int k1 = w*64 + lane;           // coalesced across lanes
        float acc1[QT], acc2[QT];
        #pragma unroll
        for (int r = 0; r < QT; ++r) { acc1[r] = 0.f; acc2[r] = 0.f; }

        #pragma unroll
        for (int d0 = 0; d0 < 64; d0 += 4) {
            const float* col = &Ktb[(size_t)d0 * SS + k1];
            const float a0 = col[0*SS], a1 = col[1*SS], a2 = col[2*SS], a3 = col[3*SS];
            const float b0 = col[0*SS+512], b1 = col[1*SS+512],
                        b2 = col[2*SS+512], b3 = col[3*SS+512];
            #pragma unroll
            for (int r = 0; r < QT; ++r) {
                const float4 q4 = *(const float4*)&sQ[r][d0];   // bcast, free
                float t1 = acc1[r], t2 = acc2[r];
                t1 = fmaf(a0, q4.x, t1); t2 = fmaf(b0, q4.x, t2);
                t1 = fmaf(a1, q4.y, t1); t2 = fmaf(b1, q4.y, t2);
                t1 = fmaf(a2, q4.z, t1); t2 = fmaf(b2, q4.z, t2);
                t1 = fmaf(a3, q4.w, t1); t2 = fmaf(b3, q4.w, t2);
                acc1[r] = t1; acc2[r] = t2;
            }
        }
        #pragma unroll
        for (int r = 0; r < QT; ++r) {
            sS[r][k1]       = acc1[r] * 0.125f;   // 1/sqrt(64)
            sS[r][k1 + 512] = acc2[r] * 0.125f;
        }
    }
    __syncthreads();

    // ---------- phase 2: wave w owns rows 2w, 2w+1 ----------
    #pragma unroll 1
    for (int rr = 0; rr < 2; ++rr) {
        const int r = w*2 + rr;
        const int q = q0 + r;

        float sv[16], ex[16];
        #pragma unroll
        for (int seg = 0; seg < 4; ++seg) {
            const float4 t = *(const float4*)&sS[r][seg*256 + lane*4];  // conflict-free
            sv[seg*4+0] = t.x; sv[seg*4+1] = t.y; sv[seg*4+2] = t.z; sv[seg*4+3] = t.w;
        }
        float m1 = -INFINITY;
        #pragma unroll
        for (int t = 0; t < 16; ++t) m1 = fmaxf(m1, sv[t]);
        #pragma unroll
        for (int off = 32; off; off >>= 1) m1 = fmaxf(m1, __shfl_xor(m1, off, 64));
        float s1 = 0.f;
        #pragma unroll
        for (int t = 0; t < 16; ++t) { ex[t] = __expf(sv[t] - m1); s1 += ex[t]; }
        #pragma unroll
        for (int off = 32; off; off >>= 1) s1 += __shfl_xor(s1, off, 64);
        const float inv_s1 = 1.f / s1;

        float pref[16], sc[4];
        #pragma unroll
        for (int seg = 0; seg < 4; ++seg) {
            float run = 0.f;
            #pragma unroll
            for (int j = 0; j < 4; ++j) {
                const int k = seg*256 + lane*4 + j;
                const float p = (k <= q) ? ex[seg*4+j] * inv_s1 : 0.f;
                run += p;
                pref[seg*4+j] = run;
            }
            sc[seg] = run;
        }
        const float ls0 = sc[0], ls1 = sc[1], ls2 = sc[2], ls3 = sc[3];
        #pragma unroll
        for (int off = 1; off < 64; off <<= 1) {
            const float t0 = __shfl_up(sc[0], off, 64);
            const float t1 = __shfl_up(sc[1], off, 64);
            const float t2 = __shfl_up(sc[2], off, 64);
            const float t3 = __shfl_up(sc[3], off, 64);
            if (lane >= off) { sc[0] += t0; sc[1] += t1; sc[2] += t2; sc[3] += t3; }
        }
        const float st0 = __shfl(sc[0], 63, 64);
        const float st1 = __shfl(sc[1], 63, 64);
        const float st2 = __shfl(sc[2], 63, 64);
        const float st3 = __shfl(sc[3], 63, 64);
        const float carry[4] = {0.f, st0, st0+st1, st0+st1+st2};
        const float excl[4]  = {sc[0]-ls0, sc[1]-ls1, sc[2]-ls2, sc[3]-ls3};
        const float total = st0 + st1 + st2 + st3;

        #pragma unroll
        for (int seg = 0; seg < 4; ++seg) {
            #pragma unroll
            for (int j = 0; j < 4; ++j) {
                const int k = seg*256 + lane*4 + j;
                const int t = seg*4 + j;
                if (k <= q) {
                    const float distcum = carry[seg] + excl[seg] + pref[t];
                    const float dsc = sqrtf(fmaxf((total - distcum) * (float)(q - k), 0.f));
                    const float te  = fminf(fmaxf(__expf(dsc * gamma), 1e-5f), 1e5f);
                    sv[t] = sv[t] * te;
                } else {
                    sv[t] = -INFINITY;
                }
            }
        }

        float m2 = -INFINITY;
        #pragma unroll
        for (int t = 0; t < 16; ++t) m2 = fmaxf(m2, sv[t]);
        #pragma unroll
        for (int off = 32; off; off >>= 1) m2 = fmaxf(m2, __shfl_xor(m2, off, 64));
        float s2 = 0.f;
        #pragma unroll
        for (int t = 0; t < 16; ++t) { ex[t] = __expf(sv[t] - m2); s2 += ex[t]; }
        #pragma unroll
        for (int off = 32; off; off >>= 1) s2 += __shfl_xor(s2, off, 64);
        const float inv2 = 1.f / s2;

        #pragma unroll
        for (int seg = 0; seg < 4; ++seg) {
            float4 o;
            o.x = ex[seg*4+0]*inv2; o.y = ex[seg*4+1]*inv2;
            o.z = ex[seg*4+2]*inv2; o.w = ex[seg*4+3]*inv2;
            *(float4*)&sS[r][seg*256 + lane*4] = o;
        }
    }
    __syncthreads();

    // ---------- phase 3: PV, k split 8-way across waves ----------
    const int kmax = q0 + QT;
    float pacc[16];
    #pragma unroll
    for (int r = 0; r < 16; ++r) pacc[r] = 0.f;

    #pragma unroll 1
    for (int k4 = w*4; k4 < kmax; k4 += 32) {
        const float va = Vb[(size_t)(k4+0)*DKK + lane];
        const float vb = Vb[(size_t)(k4+1)*DKK + lane];
        const float vc = Vb[(size_t)(k4+2)*DKK + lane];
        const float vd = Vb[(size_t)(k4+3)*DKK + lane];
        #pragma unroll
        for (int r = 0; r < 16; ++r) {
            const float4 p4 = *(const float4*)&sS[r][k4];
            pacc[r] = fmaf(p4.x, va, pacc[r]);
            pacc[r] = fmaf(p4.y, vb, pacc[r]);
            pacc[r] = fmaf(p4.z, vc, pacc[r]);
            pacc[r] = fmaf(p4.w, vd, pacc[r]);
        }
    }
    __syncthreads();

    float* scr = &sS[0][0];
    #pragma unroll
    for (int r = 0; r < 16; ++r)
        scr[(w*16 + r)*64 + lane] = pacc[r];
    __syncthreads();

    {   // reduce 8 wave-partials; write hi/lo bf16 split, concat layout
        const int r = tid >> 5, c2 = (tid & 31) << 1;
        float o0 = 0.f, o1 = 0.f;
        #pragma unroll
        for (int p = 0; p < 8; ++p) {
            const float2 s = *(const float2*)&scr[(p*16 + r)*64 + c2];
            o0 += s.x; o1 += s.y;
        }
        const size_t idx = ((size_t)(b_*SS + q0 + r))*DM + h*DKK + c2;
        ushort2 hv, lv;
        hv.x = f2bf(o0); lv.x = f2bf(o0 - bf2f(hv.x));
        hv.y = f2bf(o1); lv.y = f2bf(o1 - bf2f(hv.y));
        *(ushort2*)&AoH[idx] = hv;
        *(ushort2*)&AoL[idx] = lv;
    }
}

// ============================================================
extern "C" void kernel_launch(void* const* d_in, const int* in_sizes, int n_in,
                              void* d_out, int out_size, void* d_ws, size_t ws_size,
                              hipStream_t stream)
{
    (void)in_sizes; (void)n_in; (void)out_size; (void)ws_size;

    const float* q   = (const float*)d_in[0];
    const float* k   = (const float*)d_in[1];
    const float* v   = (const float*)d_in[2];
    const float* Wq  = (const float*)d_in[3];
    const float* bq  = (const float*)d_in[4];
    const float* Wk  = (const float*)d_in[5];
    const float* bk  = (const float*)d_in[6];
    const float* Wv  = (const float*)d_in[7];
    const float* bv  = (const float*)d_in[8];
    const float* Wo  = (const float*)d_in[9];
    const float* bo  = (const float*)d_in[10];
    const float* gam = (const float*)d_in[11];
    float* out = (float*)d_out;

    const size_t NE = (size_t)NTOK * DM;            // 4,194,304 elems
    float* Qh = (float*)d_ws;                       // fp32 16.8MB
    float* Kt = Qh + NE;                            // fp32 [B,H,DK,S]
    float* Vh = Kt + NE;                            // fp32
    u16* qh = (u16*)(Vh + NE);                      // 6 x bf16 x-splits
    u16* ql = qh + NE;
    u16* kh = ql + NE;
    u16* kl = kh + NE;
    u16* vh = kl + NE;
    u16* vl = vh + NE;
    u16* wb = vl + NE;                              // 8 x bf16 W-splits

    split_x3<<<12288, 256, 0, stream>>>(q, k, v, qh, ql, kh, kl, vh, vl);
    split_w4<<<4096,  256, 0, stream>>>(Wq, Wk, Wv, Wo, wb);

    gemm_qkv<<<768, 256, 0, stream>>>(qh, ql, kh, kl, vh, vl, wb,
                                      bq, bk, bv, Qh, Kt, Vh);

    // attn reuses qh/ql as the concat hi/lo output
    attn_kernel<<<4096, 512, 0, stream>>>(Qh, Kt, Vh, gam, qh, ql);

    gemm_out<<<512, 256, 0, stream>>>(qh, ql, wb, bo, out);
}